// Round 7
// baseline (640.062 us; speedup 1.0000x reference)
//
#include <hip/hip_runtime.h>
#include <math.h>

#define NSL 0.2f   // leaky relu negative slope
#define IN_DIM 165
#define HID 128
#define OUT_H 64
#define SCAN_B 512  // elements per scan block

typedef __attribute__((ext_vector_type(8))) short bf16x8;
typedef __attribute__((ext_vector_type(4))) float f32x4;

// ---------- bf16 pack (round-to-nearest-even) ----------
__device__ inline unsigned pack_bf16(float a, float b) {
    unsigned ua = __float_as_uint(a);
    ua += 0x7FFFu + ((ua >> 16) & 1u);
    unsigned ub = __float_as_uint(b);
    ub += 0x7FFFu + ((ub >> 16) & 1u);
    return (ua >> 16) | (ub & 0xFFFF0000u);
}
__device__ inline unsigned short bf16_1(float a) {
    unsigned ua = __float_as_uint(a);
    ua += 0x7FFFu + ((ua >> 16) & 1u);
    return (unsigned short)(ua >> 16);
}

// column permutation of the h1/g layout: flat stored col i -> original col
__device__ __host__ inline int pcol(int i) {
    int j = i >> 1, odd = i & 1;
    return 32 * (j >> 4) + (j & 15) + 16 * odd;
}

// ---------- integer degree ----------
__global__ __launch_bounds__(256) void deg_kernel(const int* __restrict__ col, int E,
                                                  int* __restrict__ degi) {
    int e = blockIdx.x * 256 + threadIdx.x;
    if (e < E) atomicAdd(&degi[col[e]], 1);
}

// ---------- block-level inclusive scan (512 elems / block) ----------
__global__ __launch_bounds__(SCAN_B) void scan_block(const int* __restrict__ degi,
                                                     int* __restrict__ incl,
                                                     int* __restrict__ bsums, int n) {
    __shared__ int tmp[SCAN_B];
    int tid = threadIdx.x;
    int gid = blockIdx.x * SCAN_B + tid;
    int v = (gid < n) ? degi[gid] : 0;
    tmp[tid] = v;
    __syncthreads();
    for (int off = 1; off < SCAN_B; off <<= 1) {
        int t = (tid >= off) ? tmp[tid - off] : 0;
        __syncthreads();
        tmp[tid] += t;
        __syncthreads();
    }
    if (gid < n) incl[gid] = tmp[tid];
    if (tid == SCAN_B - 1) bsums[blockIdx.x] = tmp[tid];
}

// ---------- single-block exclusive scan of block sums (nb <= 256) ----------
__global__ __launch_bounds__(256) void scan_bsums(int* __restrict__ bsums, int nb) {
    __shared__ int tmp[256];
    int tid = threadIdx.x;
    int v = (tid < nb) ? bsums[tid] : 0;
    tmp[tid] = v;
    __syncthreads();
    for (int off = 1; off < 256; off <<= 1) {
        int t = (tid >= off) ? tmp[tid - off] : 0;
        __syncthreads();
        tmp[tid] += t;
        __syncthreads();
    }
    if (tid < nb) bsums[tid] = tmp[tid] - v;   // exclusive
}

// ---------- finalize: exclusive offsets, dinv, bucket cursors; offsets[n]=E ----------
__global__ __launch_bounds__(256) void scan_finalize(const int* __restrict__ degi,
                                                     const int* __restrict__ bsums,
                                                     int* __restrict__ offsets,  // holds incl on entry
                                                     int* __restrict__ bcursor,
                                                     float* __restrict__ dinv,
                                                     int n, int E) {
    int gid = blockIdx.x * 256 + threadIdx.x;
    if (gid < n) {
        int excl = offsets[gid] - degi[gid] + bsums[gid >> 9];
        offsets[gid] = excl;
        dinv[gid] = rsqrtf((float)degi[gid] + 1.0f);   // +1 = self loop
        if ((gid & 31) == 0) bcursor[gid >> 5] = excl;
    } else if (gid == n) {
        offsets[n] = E;
    }
}

// ---------- phase A: scatter edges into 32-node buckets (line-friendly) ----------
__global__ __launch_bounds__(256) void bucket_scatter(const int* __restrict__ rowi,
                                                      const int* __restrict__ coli, int E,
                                                      int* __restrict__ bcursor,
                                                      uint2* __restrict__ ebuf) {
    int e = blockIdx.x * 256 + threadIdx.x;
    if (e >= E) return;
    int c = coli[e];
    int p = atomicAdd(&bcursor[c >> 5], 1);
    ebuf[p] = make_uint2((unsigned)rowi[e], (unsigned)c);
}

// ---------- phase B: one block per bucket; LDS-atomic ranks -> csr_src ----------
__global__ __launch_bounds__(256) void bucket_fill(const uint2* __restrict__ ebuf,
                                                   const int* __restrict__ offsets,
                                                   int* __restrict__ csr_src, int n) {
    __shared__ int cnt[32];
    int node0 = blockIdx.x << 5;
    if (threadIdx.x < 32) cnt[threadIdx.x] = 0;
    __syncthreads();
    int nend = min(node0 + 32, n);
    int start = offsets[node0];
    int end = offsets[nend];
    for (int e = start + threadIdx.x; e < end; e += 256) {
        uint2 rc = ebuf[e];
        int rank = atomicAdd(&cnt[rc.y & 31], 1);
        csr_src[offsets[rc.y] + rank] = (int)rc.x;
    }
}

// ---------- permuted bias ----------
__global__ __launch_bounds__(128) void b1p_kernel(const float* __restrict__ b1,
                                                  float* __restrict__ b1p) {
    int i = threadIdx.x;
    b1p[i] = b1[pcol(i)];
}

// ---------- GEMM1 via bf16 MFMA: h1p = perm-packed bf16((x@W1) * dinv[row]) ----------
// W1 LDS-resident as Ws[n][k] bf16 (stride 200, k zero-padded to 192);
// x staged per 32-K step into As (bf16, stride 20 uints). 256 thr = 4 waves;
// block = 64 rows x 128 cols; wave w owns cols [32w,32w+32); 16x16x32 MFMA.
#define KP 192
#define KWP 200
#define ASTR 20
__global__ __launch_bounds__(256) void gemm1_mfma(const float* __restrict__ x,
                                                  const float* __restrict__ W1,
                                                  const float* __restrict__ dinv,
                                                  unsigned* __restrict__ h1p, int M) {
    __shared__ unsigned short Ws[128 * KWP];
    __shared__ unsigned As[64 * ASTR];
    const int t = threadIdx.x;
    const int wave = t >> 6;
    const int lane = t & 63;
    const int l16 = lane & 15;
    const int quad = lane >> 4;
    const int row0 = blockIdx.x * 64;

    // stage W1 -> Ws[n][k] (bf16), zero-pad k >= IN_DIM
    for (int i = t; i < 128 * KP; i += 256) {
        int k = i >> 7, n = i & 127;
        float v = (k < IN_DIM) ? W1[k * 128 + n] : 0.f;
        Ws[n * KWP + k] = bf16_1(v);
    }

    f32x4 acc[4][2];
#pragma unroll
    for (int mt = 0; mt < 4; mt++)
#pragma unroll
        for (int nt = 0; nt < 2; nt++) acc[mt][nt] = (f32x4){0.f, 0.f, 0.f, 0.f};

    const int srow = t >> 2;          // staging row 0..63
    const int sk = (t & 3) * 8;       // staging k offset
    long grow = row0 + srow;
    if (grow >= M) grow = M - 1;
    const float* xrow = x + grow * IN_DIM;

    for (int kk0 = 0; kk0 < KP; kk0 += 32) {
        __syncthreads();
#pragma unroll
        for (int j = 0; j < 4; j++) {
            int k0 = kk0 + sk + 2 * j;
            float f0 = (k0 < IN_DIM) ? xrow[k0] : 0.f;
            float f1 = (k0 + 1 < IN_DIM) ? xrow[k0 + 1] : 0.f;
            As[srow * ASTR + (sk >> 1) + j] = pack_bf16(f0, f1);
        }
        __syncthreads();

        bf16x8 a[4], b[2];
#pragma unroll
        for (int mt = 0; mt < 4; mt++) {
            int m = mt * 16 + l16;
            uint4 u = *(const uint4*)&As[m * ASTR + quad * 4];
            a[mt] = __builtin_bit_cast(bf16x8, u);
        }
#pragma unroll
        for (int nt = 0; nt < 2; nt++) {
            int n = wave * 32 + nt * 16 + l16;
            uint4 u = *(const uint4*)&Ws[n * KWP + kk0 + quad * 8];
            b[nt] = __builtin_bit_cast(bf16x8, u);
        }
#pragma unroll
        for (int mt = 0; mt < 4; mt++)
#pragma unroll
            for (int nt = 0; nt < 2; nt++)
                acc[mt][nt] = __builtin_amdgcn_mfma_f32_16x16x32_bf16(
                    a[mt], b[nt], acc[mt][nt], 0, 0, 0);
    }

    // epilogue: D row = quad*4+reg, col = l16; pack (col, col+16) -> one uint
#pragma unroll
    for (int mt = 0; mt < 4; mt++) {
#pragma unroll
        for (int r = 0; r < 4; r++) {
            int row = row0 + mt * 16 + quad * 4 + r;
            if (row < M) {
                float s = dinv[row];
                h1p[(size_t)row * 64 + wave * 16 + l16] =
                    pack_bf16(acc[mt][0][r] * s, acc[mt][1][r] * s);
            }
        }
    }
}

__device__ inline void acc8(float* a, uint4 u) {
    a[0] += __uint_as_float(u.x << 16);
    a[1] += __uint_as_float(u.x & 0xFFFF0000u);
    a[2] += __uint_as_float(u.y << 16);
    a[3] += __uint_as_float(u.y & 0xFFFF0000u);
    a[4] += __uint_as_float(u.z << 16);
    a[5] += __uint_as_float(u.z & 0xFFFF0000u);
    a[6] += __uint_as_float(u.w << 16);
    a[7] += __uint_as_float(u.w & 0xFFFF0000u);
}

// ---------- GCN gather: quarter-wave (16 lanes) per dst node, bf16 rows ----------
// h1p rows pre-scaled by dinv[row] (perm layout); pure sum; epilogue *dinv[col],
// +b1p, relu; writes g in the same perm layout.
__global__ __launch_bounds__(256) void gcn_gather(const int* __restrict__ offsets,
                                                  const int* __restrict__ csr_src,
                                                  const uint4* __restrict__ h1v,
                                                  const float* __restrict__ dinv,
                                                  const float* __restrict__ b1p,
                                                  float* __restrict__ g, int n) {
    int node = (blockIdx.x * 256 + threadIdx.x) >> 4;
    int lane = threadIdx.x & 15;
    if (node >= n) return;
    int s0 = offsets[node], s1 = offsets[node + 1];

    float a0[8], a1[8], a2[8], a3[8];
#pragma unroll
    for (int i = 0; i < 8; i++) { a0[i] = 0.f; a1[i] = 0.f; a2[i] = 0.f; a3[i] = 0.f; }
    acc8(a0, h1v[(size_t)node * 16 + lane]);   // self loop (pre-scaled)

    int k = s0;
    for (; k + 4 <= s1; k += 4) {
        int r0 = csr_src[k], r1 = csr_src[k + 1], r2 = csr_src[k + 2], r3 = csr_src[k + 3];
        uint4 v0 = h1v[(size_t)r0 * 16 + lane];
        uint4 v1 = h1v[(size_t)r1 * 16 + lane];
        uint4 v2 = h1v[(size_t)r2 * 16 + lane];
        uint4 v3 = h1v[(size_t)r3 * 16 + lane];
        acc8(a0, v0);
        acc8(a1, v1);
        acc8(a2, v2);
        acc8(a3, v3);
    }
    for (; k < s1; k++) {
        int r = csr_src[k];
        acc8(a0, h1v[(size_t)r * 16 + lane]);
    }

    float dc = dinv[node];
    float4 bb0 = ((const float4*)b1p)[lane * 2];
    float4 bb1 = ((const float4*)b1p)[lane * 2 + 1];
    float4 o0, o1;
    o0.x = fmaxf(((a0[0] + a1[0]) + (a2[0] + a3[0])) * dc + bb0.x, 0.f);
    o0.y = fmaxf(((a0[1] + a1[1]) + (a2[1] + a3[1])) * dc + bb0.y, 0.f);
    o0.z = fmaxf(((a0[2] + a1[2]) + (a2[2] + a3[2])) * dc + bb0.z, 0.f);
    o0.w = fmaxf(((a0[3] + a1[3]) + (a2[3] + a3[3])) * dc + bb0.w, 0.f);
    o1.x = fmaxf(((a0[4] + a1[4]) + (a2[4] + a3[4])) * dc + bb1.x, 0.f);
    o1.y = fmaxf(((a0[5] + a1[5]) + (a2[5] + a3[5])) * dc + bb1.y, 0.f);
    o1.z = fmaxf(((a0[6] + a1[6]) + (a2[6] + a3[6])) * dc + bb1.z, 0.f);
    o1.w = fmaxf(((a0[7] + a1[7]) + (a2[7] + a3[7])) * dc + bb1.w, 0.f);
    float4* gv = (float4*)&g[(size_t)node * HID + lane * 8];
    gv[0] = o0;
    gv[1] = o1;
}

// ---------- GEMM2 + fused attention coefficients (A = g in perm layout) ----------
// Staging un-permutes: Bs[j][n] = Wg[pcol(j)][n].
__global__ __launch_bounds__(1024, 4) void gemm2_fused(const float* __restrict__ A,
                                                       const float* __restrict__ B,
                                                       const float* __restrict__ a_src,
                                                       const float* __restrict__ a_dst,
                                                       float* __restrict__ h2,
                                                       float* __restrict__ es,
                                                       float* __restrict__ ed, int M) {
    constexpr int K_ = HID, N_ = OUT_H, TM = 2, TN = 4, TX = 16;
    __shared__ float Bs[K_ * N_];
    const int t = threadIdx.x;
    const int tx = t % TX;
    const int ty = t / TX;
    const int col = tx * TN;
    constexpr int BM = (1024 / TX) * TM;   // 128
    const int row0 = blockIdx.x * BM + ty * TM;

    int rclamp[TM];
#pragma unroll
    for (int r = 0; r < TM; r++) {
        int rr = row0 + r;
        rclamp[r] = rr < M ? rr : (M - 1);
    }

    float acc[TM][TN];
#pragma unroll
    for (int r = 0; r < TM; r++)
#pragma unroll
        for (int c = 0; c < TN; c++) acc[r][c] = 0.f;

    for (int i = t; i < K_ * N_; i += 1024) {
        int j = i >> 6, n2 = i & 63;
        Bs[i] = B[pcol(j) * 64 + n2];
    }
    __syncthreads();

    for (int k = 0; k + 8 <= K_; k += 8) {
        float a[TM][8];
#pragma unroll
        for (int r = 0; r < TM; r++)
#pragma unroll
            for (int kk = 0; kk < 8; kk++)
                a[r][kk] = A[(size_t)rclamp[r] * K_ + k + kk];
#pragma unroll
        for (int kk = 0; kk < 8; kk++) {
            float b[TN];
#pragma unroll
            for (int c = 0; c < TN; c++) b[c] = Bs[(k + kk) * N_ + col + c];
#pragma unroll
            for (int r = 0; r < TM; r++)
#pragma unroll
                for (int c = 0; c < TN; c++)
                    acc[r][c] = fmaf(a[r][kk], b[c], acc[r][c]);
        }
    }

    float asv[TN], adv[TN];
#pragma unroll
    for (int c = 0; c < TN; c++) { asv[c] = a_src[col + c]; adv[c] = a_dst[col + c]; }

#pragma unroll
    for (int r = 0; r < TM; r++) {
        int gr = row0 + r;
        float ps = acc[r][0] * asv[0] + acc[r][1] * asv[1] + acc[r][2] * asv[2] + acc[r][3] * asv[3];
        float pd = acc[r][0] * adv[0] + acc[r][1] * adv[1] + acc[r][2] * adv[2] + acc[r][3] * adv[3];
#pragma unroll
        for (int m = 8; m; m >>= 1) {
            ps += __shfl_xor(ps, m, 16);
            pd += __shfl_xor(pd, m, 16);
        }
        if (gr < M) {
            float4 v = make_float4(acc[r][0], acc[r][1], acc[r][2], acc[r][3]);
            *(float4*)&h2[(size_t)gr * N_ + col] = v;
            if (tx == 0) { es[gr] = ps; ed[gr] = pd; }
        }
    }
}

// ---------- fused GAT: quarter-wave per node, float4 lanes, unnormalized softmax ----------
__global__ __launch_bounds__(256) void gat_fused(const int* __restrict__ offsets,
                                                 const int* __restrict__ csr_src,
                                                 const float4* __restrict__ h2v,  // row = 16 float4
                                                 const float* __restrict__ es,
                                                 const float* __restrict__ ed,
                                                 const float* __restrict__ bg,
                                                 const float* __restrict__ Wfc,
                                                 const float* __restrict__ bfc,
                                                 float* __restrict__ out, int n) {
    int node = (blockIdx.x * 256 + threadIdx.x) >> 4;
    int lane = threadIdx.x & 15;
    if (node >= n) return;
    int s0 = offsets[node], s1 = offsets[node + 1];
    float edc = ed[node];

    float eself = es[node] + edc;
    eself = eself > 0.f ? eself : NSL * eself;
    float x0s = __expf(eself);
    float sA = x0s, sB = 0.f, sC = 0.f, sD = 0.f;
    float4 hs = h2v[(size_t)node * 16 + lane];
    float4 aA = make_float4(x0s * hs.x, x0s * hs.y, x0s * hs.z, x0s * hs.w);
    float4 aB = make_float4(0.f, 0.f, 0.f, 0.f), aC = aB, aD = aB;

    int k = s0;
    for (; k + 4 <= s1; k += 4) {
        int r0 = csr_src[k], r1 = csr_src[k + 1], r2 = csr_src[k + 2], r3 = csr_src[k + 3];
        float e0 = es[r0] + edc, e1 = es[r1] + edc, e2 = es[r2] + edc, e3 = es[r3] + edc;
        e0 = e0 > 0.f ? e0 : NSL * e0;
        e1 = e1 > 0.f ? e1 : NSL * e1;
        e2 = e2 > 0.f ? e2 : NSL * e2;
        e3 = e3 > 0.f ? e3 : NSL * e3;
        float x0 = __expf(e0), x1 = __expf(e1), x2 = __expf(e2), x3 = __expf(e3);
        float4 v0 = h2v[(size_t)r0 * 16 + lane];
        float4 v1 = h2v[(size_t)r1 * 16 + lane];
        float4 v2 = h2v[(size_t)r2 * 16 + lane];
        float4 v3 = h2v[(size_t)r3 * 16 + lane];
        sA += x0; sB += x1; sC += x2; sD += x3;
        aA.x = fmaf(x0, v0.x, aA.x); aA.y = fmaf(x0, v0.y, aA.y);
        aA.z = fmaf(x0, v0.z, aA.z); aA.w = fmaf(x0, v0.w, aA.w);
        aB.x = fmaf(x1, v1.x, aB.x); aB.y = fmaf(x1, v1.y, aB.y);
        aB.z = fmaf(x1, v1.z, aB.z); aB.w = fmaf(x1, v1.w, aB.w);
        aC.x = fmaf(x2, v2.x, aC.x); aC.y = fmaf(x2, v2.y, aC.y);
        aC.z = fmaf(x2, v2.z, aC.z); aC.w = fmaf(x2, v2.w, aC.w);
        aD.x = fmaf(x3, v3.x, aD.x); aD.y = fmaf(x3, v3.y, aD.y);
        aD.z = fmaf(x3, v3.z, aD.z); aD.w = fmaf(x3, v3.w, aD.w);
    }
    for (; k < s1; k++) {
        int r = csr_src[k];
        float e = es[r] + edc;
        e = e > 0.f ? e : NSL * e;
        float xv = __expf(e);
        float4 hv = h2v[(size_t)r * 16 + lane];
        sA += xv;
        aA.x = fmaf(xv, hv.x, aA.x); aA.y = fmaf(xv, hv.y, aA.y);
        aA.z = fmaf(xv, hv.z, aA.z); aA.w = fmaf(xv, hv.w, aA.w);
    }
    float s = (sA + sB) + (sC + sD);
    float rcp = 1.0f / s;
    float4 bb = ((const float4*)bg)[lane];
    float ox = fmaxf(((aA.x + aB.x) + (aC.x + aD.x)) * rcp + bb.x, 0.f);
    float oy = fmaxf(((aA.y + aB.y) + (aC.y + aD.y)) * rcp + bb.y, 0.f);
    float oz = fmaxf(((aA.z + aB.z) + (aC.z + aD.z)) * rcp + bb.z, 0.f);
    float ow = fmaxf(((aA.w + aB.w) + (aC.w + aD.w)) * rcp + bb.w, 0.f);
    float4 w0 = ((const float4*)Wfc)[lane * 2];
    float4 w1 = ((const float4*)Wfc)[lane * 2 + 1];
    float p0 = ox * w0.x + oy * w0.z + oz * w1.x + ow * w1.z;
    float p1 = ox * w0.y + oy * w0.w + oz * w1.y + ow * w1.w;
#pragma unroll
    for (int m = 8; m; m >>= 1) {
        p0 += __shfl_xor(p0, m, 16);
        p1 += __shfl_xor(p1, m, 16);
    }
    if (lane == 0) {
        out[(size_t)node * 2 + 0] = p0 + bfc[0];
        out[(size_t)node * 2 + 1] = p1 + bfc[1];
    }
}

extern "C" void kernel_launch(void* const* d_in, const int* in_sizes, int n_in,
                              void* d_out, int out_size, void* d_ws, size_t ws_size,
                              hipStream_t stream) {
    const float* x     = (const float*)d_in[0];
    const int*   ei    = (const int*)d_in[1];
    const float* W1    = (const float*)d_in[2];
    const float* b1    = (const float*)d_in[3];
    const float* Wg    = (const float*)d_in[4];
    const float* a_src = (const float*)d_in[5];
    const float* a_dst = (const float*)d_in[6];
    const float* bg    = (const float*)d_in[7];
    const float* Wfc   = (const float*)d_in[8];
    const float* bfc   = (const float*)d_in[9];
    float* out = (float*)d_out;

    const int N = in_sizes[0] / IN_DIM;
    const int E = in_sizes[1] / 2;
    const int* rowi = ei;
    const int* coli = ei + E;
    const int NB = (N + 31) >> 5;   // 32-node buckets

    // workspace layout (4-byte units), ~197N + 3E ≈ 98 MB
    char* wsb = (char*)d_ws;
    int*   degi    = (int*)wsb;                         // N
    int*   offsets = degi + N;                          // N+8
    float* dinv    = (float*)(offsets + N + 8);         // N
    float* es      = dinv + N;                          // N
    float* ed      = es + N;                            // N
    int*   bcursor = (int*)(ed + N);                    // NB (+pad to even)
    int*   bsums   = bcursor + ((NB + 9) & ~1);         // 512
    float* b1p     = (float*)(bsums + 512);             // 128
    int*   csr_src = (int*)(b1p + 128);                 // E
    uint2* ebuf    = (uint2*)(csr_src + ((E + 1) & ~1));// E uint2 (8B aligned)
    unsigned* h1p  = (unsigned*)(ebuf + E);             // N*64 (bf16 pairs, perm layout)
    float* g       = (float*)(h1p + (size_t)N * 64);    // N*128 (perm layout)
    float* h2      = (float*)h1p;                       // alias: h1p dead after gcn_gather

    hipMemsetAsync(degi, 0, (size_t)N * 4, stream);

    const int nbScan = (N + SCAN_B - 1) / SCAN_B;

    // 1) degree -> scan -> offsets/dinv/bucket cursors
    deg_kernel<<<(E + 255) / 256, 256, 0, stream>>>(coli, E, degi);
    scan_block<<<nbScan, SCAN_B, 0, stream>>>(degi, offsets, bsums, N);
    scan_bsums<<<1, 256, 0, stream>>>(bsums, nbScan);
    scan_finalize<<<(N + 256) / 256, 256, 0, stream>>>(degi, bsums, offsets, bcursor, dinv, N, E);

    // 2) two-phase CSR build (bucketed for write locality)
    bucket_scatter<<<(E + 255) / 256, 256, 0, stream>>>(rowi, coli, E, bcursor, ebuf);
    bucket_fill<<<NB, 256, 0, stream>>>(ebuf, offsets, csr_src, N);

    // 3) permuted bias
    b1p_kernel<<<1, 128, 0, stream>>>(b1, b1p);

    // 4) h1p = perm-packed bf16((x @ W1) * dinv[row])  via MFMA
    gemm1_mfma<<<(N + 63) / 64, 256, 0, stream>>>(x, W1, dinv, h1p, N);

    // 5) GCN gather (pure-sum aggregation, fused dinv[col]*, bias, relu)
    gcn_gather<<<(N + 15) / 16, 256, 0, stream>>>(offsets, csr_src, (const uint4*)h1p,
                                                  dinv, b1p, g, N);

    // 6) h2 = g @ Wg with fused es/ed epilogue (un-permutes via Wg staging)
    gemm2_fused<<<(N + 127) / 128, 1024, 0, stream>>>(g, Wg, a_src, a_dst, h2, es, ed, N);

    // 7) fused GAT: unnormalized-softmax gather + relu + final FC
    gat_fused<<<(N + 15) / 16, 256, 0, stream>>>(offsets, csr_src, (const float4*)h2,
                                                 es, ed, bg, Wfc, bfc, out, N);
}

// Round 8
// 489.468 us; speedup vs baseline: 1.3077x; 1.3077x over previous
//
#include <hip/hip_runtime.h>
#include <math.h>

#define NSL 0.2f   // leaky relu negative slope
#define IN_DIM 165
#define HID 128
#define OUT_H 64
#define SCAN_B 512  // elements per scan block
#define NCB_MAX 512 // max coarse buckets (N <= 131072)
#define EPB 4096    // edges per pass1 block

typedef __attribute__((ext_vector_type(8))) short bf16x8;
typedef __attribute__((ext_vector_type(4))) float f32x4;

// ---------- bf16 pack (round-to-nearest-even) ----------
__device__ inline unsigned pack_bf16(float a, float b) {
    unsigned ua = __float_as_uint(a);
    ua += 0x7FFFu + ((ua >> 16) & 1u);
    unsigned ub = __float_as_uint(b);
    ub += 0x7FFFu + ((ub >> 16) & 1u);
    return (ua >> 16) | (ub & 0xFFFF0000u);
}
__device__ inline unsigned short bf16_1(float a) {
    unsigned ua = __float_as_uint(a);
    ua += 0x7FFFu + ((ua >> 16) & 1u);
    return (unsigned short)(ua >> 16);
}

// column permutation of the h1/g layout: flat stored col i -> original col
__device__ __host__ inline int pcol(int i) {
    int j = i >> 1, odd = i & 1;
    return 32 * (j >> 4) + (j & 15) + 16 * odd;
}

// ---------- coarse histogram (LDS-privatized) ----------
__global__ __launch_bounds__(256) void chist(const int* __restrict__ coli, int E,
                                             int* __restrict__ ghist, int ncb) {
    __shared__ int h[NCB_MAX];
    for (int i = threadIdx.x; i < ncb; i += 256) h[i] = 0;
    __syncthreads();
    int e0 = blockIdx.x * EPB;
    int e1 = min(e0 + EPB, E);
    for (int e = e0 + threadIdx.x; e < e1; e += 256)
        atomicAdd(&h[coli[e] >> 8], 1);
    __syncthreads();
    for (int i = threadIdx.x; i < ncb; i += 256)
        if (h[i]) atomicAdd(&ghist[i], h[i]);
}

// ---------- 1-block scan of coarse histogram -> cstart, gcursor ----------
__global__ __launch_bounds__(NCB_MAX) void cscan(const int* __restrict__ ghist,
                                                 int* __restrict__ cstart,
                                                 int* __restrict__ gcursor,
                                                 int ncb, int E) {
    __shared__ int tmp[NCB_MAX];
    int tid = threadIdx.x;
    int v = (tid < ncb) ? ghist[tid] : 0;
    tmp[tid] = v;
    __syncthreads();
    for (int off = 1; off < NCB_MAX; off <<= 1) {
        int t = (tid >= off) ? tmp[tid - off] : 0;
        __syncthreads();
        tmp[tid] += t;
        __syncthreads();
    }
    if (tid < ncb) {
        int excl = tmp[tid] - v;
        cstart[tid] = excl;
        gcursor[tid] = excl;
    }
    if (tid == ncb - 1) cstart[ncb] = E;
}

// ---------- pass1: block-privatized scatter into coarse buckets ----------
// ebuf value = (row << 8) | (col & 255)   (requires N < 2^24)
__global__ __launch_bounds__(256) void pass1_scatter(const int* __restrict__ rowi,
                                                     const int* __restrict__ coli, int E,
                                                     int* __restrict__ gcursor,
                                                     unsigned* __restrict__ ebuf, int ncb) {
    __shared__ int hist[NCB_MAX];
    __shared__ int base[NCB_MAX];
    int e0 = blockIdx.x * EPB;
    int e1 = min(e0 + EPB, E);
    for (int i = threadIdx.x; i < ncb; i += 256) hist[i] = 0;
    __syncthreads();
    for (int e = e0 + threadIdx.x; e < e1; e += 256)
        atomicAdd(&hist[coli[e] >> 8], 1);
    __syncthreads();
    for (int i = threadIdx.x; i < ncb; i += 256) {
        int h = hist[i];
        base[i] = h ? atomicAdd(&gcursor[i], h) : 0;
        hist[i] = 0;
    }
    __syncthreads();
    for (int e = e0 + threadIdx.x; e < e1; e += 256) {
        int c = coli[e];
        int cb = c >> 8;
        int rank = atomicAdd(&hist[cb], 1);
        ebuf[base[cb] + rank] = ((unsigned)rowi[e] << 8) | (unsigned)(c & 255);
    }
}

// ---------- pass2a: per-bucket fine-degree count -> degi (coalesced write) ----------
__global__ __launch_bounds__(256) void pass2_count(const unsigned* __restrict__ ebuf,
                                                   const int* __restrict__ cstart,
                                                   int* __restrict__ degi, int n) {
    __shared__ int cnt[256];
    int cb = blockIdx.x;
    cnt[threadIdx.x] = 0;
    __syncthreads();
    int s = cstart[cb], e1 = cstart[cb + 1];
    for (int e = s + threadIdx.x; e < e1; e += 256)
        atomicAdd(&cnt[ebuf[e] & 255u], 1);
    __syncthreads();
    int node = (cb << 8) + threadIdx.x;
    if (node < n) degi[node] = cnt[threadIdx.x];
}

// ---------- block-level inclusive scan (512 elems / block) ----------
__global__ __launch_bounds__(SCAN_B) void scan_block(const int* __restrict__ degi,
                                                     int* __restrict__ incl,
                                                     int* __restrict__ bsums, int n) {
    __shared__ int tmp[SCAN_B];
    int tid = threadIdx.x;
    int gid = blockIdx.x * SCAN_B + tid;
    int v = (gid < n) ? degi[gid] : 0;
    tmp[tid] = v;
    __syncthreads();
    for (int off = 1; off < SCAN_B; off <<= 1) {
        int t = (tid >= off) ? tmp[tid - off] : 0;
        __syncthreads();
        tmp[tid] += t;
        __syncthreads();
    }
    if (gid < n) incl[gid] = tmp[tid];
    if (tid == SCAN_B - 1) bsums[blockIdx.x] = tmp[tid];
}

// ---------- single-block exclusive scan of block sums (nb <= 256) ----------
__global__ __launch_bounds__(256) void scan_bsums(int* __restrict__ bsums, int nb) {
    __shared__ int tmp[256];
    int tid = threadIdx.x;
    int v = (tid < nb) ? bsums[tid] : 0;
    tmp[tid] = v;
    __syncthreads();
    for (int off = 1; off < 256; off <<= 1) {
        int t = (tid >= off) ? tmp[tid - off] : 0;
        __syncthreads();
        tmp[tid] += t;
        __syncthreads();
    }
    if (tid < nb) bsums[tid] = tmp[tid] - v;   // exclusive
}

// ---------- finalize: exclusive offsets, dinv; offsets[n]=E ----------
__global__ __launch_bounds__(256) void scan_finalize(const int* __restrict__ degi,
                                                     const int* __restrict__ bsums,
                                                     int* __restrict__ offsets,  // holds incl on entry
                                                     float* __restrict__ dinv,
                                                     int n, int E) {
    int gid = blockIdx.x * 256 + threadIdx.x;
    if (gid < n) {
        int excl = offsets[gid] - degi[gid] + bsums[gid >> 9];
        offsets[gid] = excl;
        dinv[gid] = rsqrtf((float)degi[gid] + 1.0f);   // +1 = self loop
    } else if (gid == n) {
        offsets[n] = E;
    }
}

// ---------- pass2b: per-bucket rank + fill csr_src (block-exclusive window) ----------
__global__ __launch_bounds__(256) void pass2_fill(const unsigned* __restrict__ ebuf,
                                                  const int* __restrict__ cstart,
                                                  const int* __restrict__ offsets,
                                                  int* __restrict__ csr_src, int n) {
    __shared__ int cnt[256];
    __shared__ int offs[256];
    int cb = blockIdx.x;
    int node = (cb << 8) + threadIdx.x;
    cnt[threadIdx.x] = 0;
    offs[threadIdx.x] = (node < n) ? offsets[node] : 0;
    __syncthreads();
    int s = cstart[cb], e1 = cstart[cb + 1];
    for (int e = s + threadIdx.x; e < e1; e += 256) {
        unsigned v = ebuf[e];
        int local = v & 255u;
        int rank = atomicAdd(&cnt[local], 1);
        csr_src[offs[local] + rank] = (int)(v >> 8);
    }
}

// ---------- permuted bias ----------
__global__ __launch_bounds__(128) void b1p_kernel(const float* __restrict__ b1,
                                                  float* __restrict__ b1p) {
    int i = threadIdx.x;
    b1p[i] = b1[pcol(i)];
}

// ---------- GEMM1 via bf16 MFMA: h1p = perm-packed bf16((x@W1) * dinv[row]) ----------
#define KP 192
#define KWP 200
#define ASTR 20
__global__ __launch_bounds__(256) void gemm1_mfma(const float* __restrict__ x,
                                                  const float* __restrict__ W1,
                                                  const float* __restrict__ dinv,
                                                  unsigned* __restrict__ h1p, int M) {
    __shared__ unsigned short Ws[128 * KWP];
    __shared__ unsigned As[64 * ASTR];
    const int t = threadIdx.x;
    const int wave = t >> 6;
    const int lane = t & 63;
    const int l16 = lane & 15;
    const int quad = lane >> 4;
    const int row0 = blockIdx.x * 64;

    for (int i = t; i < 128 * KP; i += 256) {
        int k = i >> 7, n = i & 127;
        float v = (k < IN_DIM) ? W1[k * 128 + n] : 0.f;
        Ws[n * KWP + k] = bf16_1(v);
    }

    f32x4 acc[4][2];
#pragma unroll
    for (int mt = 0; mt < 4; mt++)
#pragma unroll
        for (int nt = 0; nt < 2; nt++) acc[mt][nt] = (f32x4){0.f, 0.f, 0.f, 0.f};

    const int srow = t >> 2;
    const int sk = (t & 3) * 8;
    long grow = row0 + srow;
    if (grow >= M) grow = M - 1;
    const float* xrow = x + grow * IN_DIM;

    for (int kk0 = 0; kk0 < KP; kk0 += 32) {
        __syncthreads();
#pragma unroll
        for (int j = 0; j < 4; j++) {
            int k0 = kk0 + sk + 2 * j;
            float f0 = (k0 < IN_DIM) ? xrow[k0] : 0.f;
            float f1 = (k0 + 1 < IN_DIM) ? xrow[k0 + 1] : 0.f;
            As[srow * ASTR + (sk >> 1) + j] = pack_bf16(f0, f1);
        }
        __syncthreads();

        bf16x8 a[4], b[2];
#pragma unroll
        for (int mt = 0; mt < 4; mt++) {
            int m = mt * 16 + l16;
            uint4 u = *(const uint4*)&As[m * ASTR + quad * 4];
            a[mt] = __builtin_bit_cast(bf16x8, u);
        }
#pragma unroll
        for (int nt = 0; nt < 2; nt++) {
            int n = wave * 32 + nt * 16 + l16;
            uint4 u = *(const uint4*)&Ws[n * KWP + kk0 + quad * 8];
            b[nt] = __builtin_bit_cast(bf16x8, u);
        }
#pragma unroll
        for (int mt = 0; mt < 4; mt++)
#pragma unroll
            for (int nt = 0; nt < 2; nt++)
                acc[mt][nt] = __builtin_amdgcn_mfma_f32_16x16x32_bf16(
                    a[mt], b[nt], acc[mt][nt], 0, 0, 0);
    }

#pragma unroll
    for (int mt = 0; mt < 4; mt++) {
#pragma unroll
        for (int r = 0; r < 4; r++) {
            int row = row0 + mt * 16 + quad * 4 + r;
            if (row < M) {
                float s = dinv[row];
                h1p[(size_t)row * 64 + wave * 16 + l16] =
                    pack_bf16(acc[mt][0][r] * s, acc[mt][1][r] * s);
            }
        }
    }
}

__device__ inline void acc8(float* a, uint4 u) {
    a[0] += __uint_as_float(u.x << 16);
    a[1] += __uint_as_float(u.x & 0xFFFF0000u);
    a[2] += __uint_as_float(u.y << 16);
    a[3] += __uint_as_float(u.y & 0xFFFF0000u);
    a[4] += __uint_as_float(u.z << 16);
    a[5] += __uint_as_float(u.z & 0xFFFF0000u);
    a[6] += __uint_as_float(u.w << 16);
    a[7] += __uint_as_float(u.w & 0xFFFF0000u);
}

// ---------- GCN gather: quarter-wave (16 lanes) per dst node, bf16 rows ----------
__global__ __launch_bounds__(256) void gcn_gather(const int* __restrict__ offsets,
                                                  const int* __restrict__ csr_src,
                                                  const uint4* __restrict__ h1v,
                                                  const float* __restrict__ dinv,
                                                  const float* __restrict__ b1p,
                                                  float* __restrict__ g, int n) {
    int node = (blockIdx.x * 256 + threadIdx.x) >> 4;
    int lane = threadIdx.x & 15;
    if (node >= n) return;
    int s0 = offsets[node], s1 = offsets[node + 1];

    float a0[8], a1[8], a2[8], a3[8];
#pragma unroll
    for (int i = 0; i < 8; i++) { a0[i] = 0.f; a1[i] = 0.f; a2[i] = 0.f; a3[i] = 0.f; }
    acc8(a0, h1v[(size_t)node * 16 + lane]);   // self loop (pre-scaled)

    int k = s0;
    for (; k + 4 <= s1; k += 4) {
        int r0 = csr_src[k], r1 = csr_src[k + 1], r2 = csr_src[k + 2], r3 = csr_src[k + 3];
        uint4 v0 = h1v[(size_t)r0 * 16 + lane];
        uint4 v1 = h1v[(size_t)r1 * 16 + lane];
        uint4 v2 = h1v[(size_t)r2 * 16 + lane];
        uint4 v3 = h1v[(size_t)r3 * 16 + lane];
        acc8(a0, v0);
        acc8(a1, v1);
        acc8(a2, v2);
        acc8(a3, v3);
    }
    for (; k < s1; k++) {
        int r = csr_src[k];
        acc8(a0, h1v[(size_t)r * 16 + lane]);
    }

    float dc = dinv[node];
    float4 bb0 = ((const float4*)b1p)[lane * 2];
    float4 bb1 = ((const float4*)b1p)[lane * 2 + 1];
    float4 o0, o1;
    o0.x = fmaxf(((a0[0] + a1[0]) + (a2[0] + a3[0])) * dc + bb0.x, 0.f);
    o0.y = fmaxf(((a0[1] + a1[1]) + (a2[1] + a3[1])) * dc + bb0.y, 0.f);
    o0.z = fmaxf(((a0[2] + a1[2]) + (a2[2] + a3[2])) * dc + bb0.z, 0.f);
    o0.w = fmaxf(((a0[3] + a1[3]) + (a2[3] + a3[3])) * dc + bb0.w, 0.f);
    o1.x = fmaxf(((a0[4] + a1[4]) + (a2[4] + a3[4])) * dc + bb1.x, 0.f);
    o1.y = fmaxf(((a0[5] + a1[5]) + (a2[5] + a3[5])) * dc + bb1.y, 0.f);
    o1.z = fmaxf(((a0[6] + a1[6]) + (a2[6] + a3[6])) * dc + bb1.z, 0.f);
    o1.w = fmaxf(((a0[7] + a1[7]) + (a2[7] + a3[7])) * dc + bb1.w, 0.f);
    float4* gv = (float4*)&g[(size_t)node * HID + lane * 8];
    gv[0] = o0;
    gv[1] = o1;
}

// ---------- GEMM2 + fused attention coefficients (A = g in perm layout) ----------
__global__ __launch_bounds__(1024, 4) void gemm2_fused(const float* __restrict__ A,
                                                       const float* __restrict__ B,
                                                       const float* __restrict__ a_src,
                                                       const float* __restrict__ a_dst,
                                                       float* __restrict__ h2,
                                                       float* __restrict__ es,
                                                       float* __restrict__ ed, int M) {
    constexpr int K_ = HID, N_ = OUT_H, TM = 2, TN = 4, TX = 16;
    __shared__ float Bs[K_ * N_];
    const int t = threadIdx.x;
    const int tx = t % TX;
    const int ty = t / TX;
    const int col = tx * TN;
    constexpr int BM = (1024 / TX) * TM;   // 128
    const int row0 = blockIdx.x * BM + ty * TM;

    int rclamp[TM];
#pragma unroll
    for (int r = 0; r < TM; r++) {
        int rr = row0 + r;
        rclamp[r] = rr < M ? rr : (M - 1);
    }

    float acc[TM][TN];
#pragma unroll
    for (int r = 0; r < TM; r++)
#pragma unroll
        for (int c = 0; c < TN; c++) acc[r][c] = 0.f;

    for (int i = t; i < K_ * N_; i += 1024) {
        int j = i >> 6, n2 = i & 63;
        Bs[i] = B[pcol(j) * 64 + n2];
    }
    __syncthreads();

    for (int k = 0; k + 8 <= K_; k += 8) {
        float a[TM][8];
#pragma unroll
        for (int r = 0; r < TM; r++)
#pragma unroll
            for (int kk = 0; kk < 8; kk++)
                a[r][kk] = A[(size_t)rclamp[r] * K_ + k + kk];
#pragma unroll
        for (int kk = 0; kk < 8; kk++) {
            float b[TN];
#pragma unroll
            for (int c = 0; c < TN; c++) b[c] = Bs[(k + kk) * N_ + col + c];
#pragma unroll
            for (int r = 0; r < TM; r++)
#pragma unroll
                for (int c = 0; c < TN; c++)
                    acc[r][c] = fmaf(a[r][kk], b[c], acc[r][c]);
        }
    }

    float asv[TN], adv[TN];
#pragma unroll
    for (int c = 0; c < TN; c++) { asv[c] = a_src[col + c]; adv[c] = a_dst[col + c]; }

#pragma unroll
    for (int r = 0; r < TM; r++) {
        int gr = row0 + r;
        float ps = acc[r][0] * asv[0] + acc[r][1] * asv[1] + acc[r][2] * asv[2] + acc[r][3] * asv[3];
        float pd = acc[r][0] * adv[0] + acc[r][1] * adv[1] + acc[r][2] * adv[2] + acc[r][3] * adv[3];
#pragma unroll
        for (int m = 8; m; m >>= 1) {
            ps += __shfl_xor(ps, m, 16);
            pd += __shfl_xor(pd, m, 16);
        }
        if (gr < M) {
            float4 v = make_float4(acc[r][0], acc[r][1], acc[r][2], acc[r][3]);
            *(float4*)&h2[(size_t)gr * N_ + col] = v;
            if (tx == 0) { es[gr] = ps; ed[gr] = pd; }
        }
    }
}

// ---------- fused GAT: quarter-wave per node, float4 lanes, unnormalized softmax ----------
__global__ __launch_bounds__(256) void gat_fused(const int* __restrict__ offsets,
                                                 const int* __restrict__ csr_src,
                                                 const float4* __restrict__ h2v,
                                                 const float* __restrict__ es,
                                                 const float* __restrict__ ed,
                                                 const float* __restrict__ bg,
                                                 const float* __restrict__ Wfc,
                                                 const float* __restrict__ bfc,
                                                 float* __restrict__ out, int n) {
    int node = (blockIdx.x * 256 + threadIdx.x) >> 4;
    int lane = threadIdx.x & 15;
    if (node >= n) return;
    int s0 = offsets[node], s1 = offsets[node + 1];
    float edc = ed[node];

    float eself = es[node] + edc;
    eself = eself > 0.f ? eself : NSL * eself;
    float x0s = __expf(eself);
    float sA = x0s, sB = 0.f, sC = 0.f, sD = 0.f;
    float4 hs = h2v[(size_t)node * 16 + lane];
    float4 aA = make_float4(x0s * hs.x, x0s * hs.y, x0s * hs.z, x0s * hs.w);
    float4 aB = make_float4(0.f, 0.f, 0.f, 0.f), aC = aB, aD = aB;

    int k = s0;
    for (; k + 4 <= s1; k += 4) {
        int r0 = csr_src[k], r1 = csr_src[k + 1], r2 = csr_src[k + 2], r3 = csr_src[k + 3];
        float e0 = es[r0] + edc, e1 = es[r1] + edc, e2 = es[r2] + edc, e3 = es[r3] + edc;
        e0 = e0 > 0.f ? e0 : NSL * e0;
        e1 = e1 > 0.f ? e1 : NSL * e1;
        e2 = e2 > 0.f ? e2 : NSL * e2;
        e3 = e3 > 0.f ? e3 : NSL * e3;
        float x0 = __expf(e0), x1 = __expf(e1), x2 = __expf(e2), x3 = __expf(e3);
        float4 v0 = h2v[(size_t)r0 * 16 + lane];
        float4 v1 = h2v[(size_t)r1 * 16 + lane];
        float4 v2 = h2v[(size_t)r2 * 16 + lane];
        float4 v3 = h2v[(size_t)r3 * 16 + lane];
        sA += x0; sB += x1; sC += x2; sD += x3;
        aA.x = fmaf(x0, v0.x, aA.x); aA.y = fmaf(x0, v0.y, aA.y);
        aA.z = fmaf(x0, v0.z, aA.z); aA.w = fmaf(x0, v0.w, aA.w);
        aB.x = fmaf(x1, v1.x, aB.x); aB.y = fmaf(x1, v1.y, aB.y);
        aB.z = fmaf(x1, v1.z, aB.z); aB.w = fmaf(x1, v1.w, aB.w);
        aC.x = fmaf(x2, v2.x, aC.x); aC.y = fmaf(x2, v2.y, aC.y);
        aC.z = fmaf(x2, v2.z, aC.z); aC.w = fmaf(x2, v2.w, aC.w);
        aD.x = fmaf(x3, v3.x, aD.x); aD.y = fmaf(x3, v3.y, aD.y);
        aD.z = fmaf(x3, v3.z, aD.z); aD.w = fmaf(x3, v3.w, aD.w);
    }
    for (; k < s1; k++) {
        int r = csr_src[k];
        float e = es[r] + edc;
        e = e > 0.f ? e : NSL * e;
        float xv = __expf(e);
        float4 hv = h2v[(size_t)r * 16 + lane];
        sA += xv;
        aA.x = fmaf(xv, hv.x, aA.x); aA.y = fmaf(xv, hv.y, aA.y);
        aA.z = fmaf(xv, hv.z, aA.z); aA.w = fmaf(xv, hv.w, aA.w);
    }
    float s = (sA + sB) + (sC + sD);
    float rcp = 1.0f / s;
    float4 bb = ((const float4*)bg)[lane];
    float ox = fmaxf(((aA.x + aB.x) + (aC.x + aD.x)) * rcp + bb.x, 0.f);
    float oy = fmaxf(((aA.y + aB.y) + (aC.y + aD.y)) * rcp + bb.y, 0.f);
    float oz = fmaxf(((aA.z + aB.z) + (aC.z + aD.z)) * rcp + bb.z, 0.f);
    float ow = fmaxf(((aA.w + aB.w) + (aC.w + aD.w)) * rcp + bb.w, 0.f);
    float4 w0 = ((const float4*)Wfc)[lane * 2];
    float4 w1 = ((const float4*)Wfc)[lane * 2 + 1];
    float p0 = ox * w0.x + oy * w0.z + oz * w1.x + ow * w1.z;
    float p1 = ox * w0.y + oy * w0.w + oz * w1.y + ow * w1.w;
#pragma unroll
    for (int m = 8; m; m >>= 1) {
        p0 += __shfl_xor(p0, m, 16);
        p1 += __shfl_xor(p1, m, 16);
    }
    if (lane == 0) {
        out[(size_t)node * 2 + 0] = p0 + bfc[0];
        out[(size_t)node * 2 + 1] = p1 + bfc[1];
    }
}

extern "C" void kernel_launch(void* const* d_in, const int* in_sizes, int n_in,
                              void* d_out, int out_size, void* d_ws, size_t ws_size,
                              hipStream_t stream) {
    const float* x     = (const float*)d_in[0];
    const int*   ei    = (const int*)d_in[1];
    const float* W1    = (const float*)d_in[2];
    const float* b1    = (const float*)d_in[3];
    const float* Wg    = (const float*)d_in[4];
    const float* a_src = (const float*)d_in[5];
    const float* a_dst = (const float*)d_in[6];
    const float* bg    = (const float*)d_in[7];
    const float* Wfc   = (const float*)d_in[8];
    const float* bfc   = (const float*)d_in[9];
    float* out = (float*)d_out;

    const int N = in_sizes[0] / IN_DIM;
    const int E = in_sizes[1] / 2;
    const int* rowi = ei;
    const int* coli = ei + E;
    const int ncb = (N + 255) >> 8;            // coarse buckets of 256 nodes

    // workspace layout (4-byte units), ~197N + 2E + small ≈ 92 MB
    char* wsb = (char*)d_ws;
    int*   degi    = (int*)wsb;                         // N
    int*   offsets = degi + N;                          // N+8
    float* dinv    = (float*)(offsets + N + 8);         // N
    float* es      = dinv + N;                          // N
    float* ed      = es + N;                            // N
    int*   ghist   = (int*)(ed + N);                    // NCB_MAX
    int*   cstart  = ghist + NCB_MAX;                   // NCB_MAX+2
    int*   gcursor = cstart + NCB_MAX + 2;              // NCB_MAX
    int*   bsums   = gcursor + NCB_MAX;                 // 512
    float* b1p     = (float*)(bsums + 512);             // 128
    int*   csr_src = (int*)(b1p + 128);                 // E
    unsigned* ebuf = (unsigned*)(csr_src + E);          // E (packed row<<8|local)
    unsigned* h1p  = (unsigned*)(ebuf + E);             // N*64 (bf16 pairs, perm layout)
    float* g       = (float*)(h1p + (size_t)N * 64);    // N*128 (perm layout)
    float* h2      = (float*)h1p;                       // alias: h1p dead after gcn_gather

    hipMemsetAsync(ghist, 0, NCB_MAX * 4, stream);

    const int nbE = (E + EPB - 1) / EPB;
    const int nbScan = (N + SCAN_B - 1) / SCAN_B;

    // 1) CSR build: coarse hist -> coarse scan -> privatized scatter ->
    //    fine counts -> N-scan -> block-local fill
    chist<<<nbE, 256, 0, stream>>>(coli, E, ghist, ncb);
    cscan<<<1, NCB_MAX, 0, stream>>>(ghist, cstart, gcursor, ncb, E);
    pass1_scatter<<<nbE, 256, 0, stream>>>(rowi, coli, E, gcursor, ebuf, ncb);
    pass2_count<<<ncb, 256, 0, stream>>>(ebuf, cstart, degi, N);
    scan_block<<<nbScan, SCAN_B, 0, stream>>>(degi, offsets, bsums, N);
    scan_bsums<<<1, 256, 0, stream>>>(bsums, nbScan);
    scan_finalize<<<(N + 256) / 256, 256, 0, stream>>>(degi, bsums, offsets, dinv, N, E);
    pass2_fill<<<ncb, 256, 0, stream>>>(ebuf, cstart, offsets, csr_src, N);

    // 2) permuted bias
    b1p_kernel<<<1, 128, 0, stream>>>(b1, b1p);

    // 3) h1p = perm-packed bf16((x @ W1) * dinv[row]) via MFMA
    gemm1_mfma<<<(N + 63) / 64, 256, 0, stream>>>(x, W1, dinv, h1p, N);

    // 4) GCN gather (pure-sum aggregation, fused dinv[col]*, bias, relu)
    gcn_gather<<<(N + 15) / 16, 256, 0, stream>>>(offsets, csr_src, (const uint4*)h1p,
                                                  dinv, b1p, g, N);

    // 5) h2 = g @ Wg with fused es/ed epilogue (un-permutes via Wg staging)
    gemm2_fused<<<(N + 127) / 128, 1024, 0, stream>>>(g, Wg, a_src, a_dst, h2, es, ed, N);

    // 6) fused GAT: unnormalized-softmax gather + relu + final FC
    gat_fused<<<(N + 15) / 16, 256, 0, stream>>>(offsets, csr_src, (const float4*)h2,
                                                 es, ed, bg, Wfc, bfc, out, N);
}

// Round 9
// 439.044 us; speedup vs baseline: 1.4579x; 1.1149x over previous
//
#include <hip/hip_runtime.h>
#include <math.h>

#define NSL 0.2f   // leaky relu negative slope
#define IN_DIM 165
#define HID 128
#define OUT_H 64
#define SCAN_B 512  // elements per scan block
#define NCB_MAX 512 // max coarse buckets (N <= 131072)
#define EPB 4096    // edges per pass1 block

typedef __attribute__((ext_vector_type(8))) short bf16x8;
typedef __attribute__((ext_vector_type(4))) float f32x4;

// ---------- bf16 pack (round-to-nearest-even) ----------
__device__ inline unsigned pack_bf16(float a, float b) {
    unsigned ua = __float_as_uint(a);
    ua += 0x7FFFu + ((ua >> 16) & 1u);
    unsigned ub = __float_as_uint(b);
    ub += 0x7FFFu + ((ub >> 16) & 1u);
    return (ua >> 16) | (ub & 0xFFFF0000u);
}

// column permutation of the h1/g layout: flat stored col i -> original col
__device__ __host__ inline int pcol(int i) {
    int j = i >> 1, odd = i & 1;
    return 32 * (j >> 4) + (j & 15) + 16 * odd;
}

// ---------- coarse histogram (LDS-privatized) ----------
__global__ __launch_bounds__(256) void chist(const int* __restrict__ coli, int E,
                                             int* __restrict__ ghist, int ncb) {
    __shared__ int h[NCB_MAX];
    for (int i = threadIdx.x; i < ncb; i += 256) h[i] = 0;
    __syncthreads();
    int e0 = blockIdx.x * EPB;
    int e1 = min(e0 + EPB, E);
    for (int e = e0 + threadIdx.x; e < e1; e += 256)
        atomicAdd(&h[coli[e] >> 8], 1);
    __syncthreads();
    for (int i = threadIdx.x; i < ncb; i += 256)
        if (h[i]) atomicAdd(&ghist[i], h[i]);
}

// ---------- 1-block scan of coarse histogram -> cstart, gcursor ----------
__global__ __launch_bounds__(NCB_MAX) void cscan(const int* __restrict__ ghist,
                                                 int* __restrict__ cstart,
                                                 int* __restrict__ gcursor,
                                                 int ncb, int E) {
    __shared__ int tmp[NCB_MAX];
    int tid = threadIdx.x;
    int v = (tid < ncb) ? ghist[tid] : 0;
    tmp[tid] = v;
    __syncthreads();
    for (int off = 1; off < NCB_MAX; off <<= 1) {
        int t = (tid >= off) ? tmp[tid - off] : 0;
        __syncthreads();
        tmp[tid] += t;
        __syncthreads();
    }
    if (tid < ncb) {
        int excl = tmp[tid] - v;
        cstart[tid] = excl;
        gcursor[tid] = excl;
    }
    if (tid == ncb - 1) cstart[ncb] = E;
}

// ---------- pass1: block-privatized scatter into coarse buckets ----------
// ebuf value = (row << 8) | (col & 255)   (requires N < 2^24)
__global__ __launch_bounds__(256) void pass1_scatter(const int* __restrict__ rowi,
                                                     const int* __restrict__ coli, int E,
                                                     int* __restrict__ gcursor,
                                                     unsigned* __restrict__ ebuf, int ncb) {
    __shared__ int hist[NCB_MAX];
    __shared__ int base[NCB_MAX];
    int e0 = blockIdx.x * EPB;
    int e1 = min(e0 + EPB, E);
    for (int i = threadIdx.x; i < ncb; i += 256) hist[i] = 0;
    __syncthreads();
    for (int e = e0 + threadIdx.x; e < e1; e += 256)
        atomicAdd(&hist[coli[e] >> 8], 1);
    __syncthreads();
    for (int i = threadIdx.x; i < ncb; i += 256) {
        int h = hist[i];
        base[i] = h ? atomicAdd(&gcursor[i], h) : 0;
        hist[i] = 0;
    }
    __syncthreads();
    for (int e = e0 + threadIdx.x; e < e1; e += 256) {
        int c = coli[e];
        int cb = c >> 8;
        int rank = atomicAdd(&hist[cb], 1);
        ebuf[base[cb] + rank] = ((unsigned)rowi[e] << 8) | (unsigned)(c & 255);
    }
}

// ---------- pass2a: per-bucket fine-degree count -> degi (coalesced write) ----------
__global__ __launch_bounds__(256) void pass2_count(const unsigned* __restrict__ ebuf,
                                                   const int* __restrict__ cstart,
                                                   int* __restrict__ degi, int n) {
    __shared__ int cnt[256];
    int cb = blockIdx.x;
    cnt[threadIdx.x] = 0;
    __syncthreads();
    int s = cstart[cb], e1 = cstart[cb + 1];
    for (int e = s + threadIdx.x; e < e1; e += 256)
        atomicAdd(&cnt[ebuf[e] & 255u], 1);
    __syncthreads();
    int node = (cb << 8) + threadIdx.x;
    if (node < n) degi[node] = cnt[threadIdx.x];
}

// ---------- block-level inclusive scan (512 elems / block) ----------
__global__ __launch_bounds__(SCAN_B) void scan_block(const int* __restrict__ degi,
                                                     int* __restrict__ incl,
                                                     int* __restrict__ bsums, int n) {
    __shared__ int tmp[SCAN_B];
    int tid = threadIdx.x;
    int gid = blockIdx.x * SCAN_B + tid;
    int v = (gid < n) ? degi[gid] : 0;
    tmp[tid] = v;
    __syncthreads();
    for (int off = 1; off < SCAN_B; off <<= 1) {
        int t = (tid >= off) ? tmp[tid - off] : 0;
        __syncthreads();
        tmp[tid] += t;
        __syncthreads();
    }
    if (gid < n) incl[gid] = tmp[tid];
    if (tid == SCAN_B - 1) bsums[blockIdx.x] = tmp[tid];
}

// ---------- single-block exclusive scan of block sums (nb <= 256) ----------
__global__ __launch_bounds__(256) void scan_bsums(int* __restrict__ bsums, int nb) {
    __shared__ int tmp[256];
    int tid = threadIdx.x;
    int v = (tid < nb) ? bsums[tid] : 0;
    tmp[tid] = v;
    __syncthreads();
    for (int off = 1; off < 256; off <<= 1) {
        int t = (tid >= off) ? tmp[tid - off] : 0;
        __syncthreads();
        tmp[tid] += t;
        __syncthreads();
    }
    if (tid < nb) bsums[tid] = tmp[tid] - v;   // exclusive
}

// ---------- finalize: exclusive offsets, dinv; offsets[n]=E ----------
__global__ __launch_bounds__(256) void scan_finalize(const int* __restrict__ degi,
                                                     const int* __restrict__ bsums,
                                                     int* __restrict__ offsets,  // holds incl on entry
                                                     float* __restrict__ dinv,
                                                     int n, int E) {
    int gid = blockIdx.x * 256 + threadIdx.x;
    if (gid < n) {
        int excl = offsets[gid] - degi[gid] + bsums[gid >> 9];
        offsets[gid] = excl;
        dinv[gid] = rsqrtf((float)degi[gid] + 1.0f);   // +1 = self loop
    } else if (gid == n) {
        offsets[n] = E;
    }
}

// ---------- pass2b: per-bucket rank + fill csr_src (block-exclusive window) ----------
__global__ __launch_bounds__(256) void pass2_fill(const unsigned* __restrict__ ebuf,
                                                  const int* __restrict__ cstart,
                                                  const int* __restrict__ offsets,
                                                  int* __restrict__ csr_src, int n) {
    __shared__ int cnt[256];
    __shared__ int offs[256];
    int cb = blockIdx.x;
    int node = (cb << 8) + threadIdx.x;
    cnt[threadIdx.x] = 0;
    offs[threadIdx.x] = (node < n) ? offsets[node] : 0;
    __syncthreads();
    int s = cstart[cb], e1 = cstart[cb + 1];
    for (int e = s + threadIdx.x; e < e1; e += 256) {
        unsigned v = ebuf[e];
        int local = v & 255u;
        int rank = atomicAdd(&cnt[local], 1);
        csr_src[offs[local] + rank] = (int)(v >> 8);
    }
}

// ---------- W1 -> bf16 B-fragment layout (one-time, 48 KB) + permuted bias ----------
// wfrag[(c*128 + n)*4 + q] = uint4 of bf16 W1[c*32+q*8 .. +7][n] (k zero-padded)
__global__ __launch_bounds__(256) void wprep(const float* __restrict__ W1,
                                             const float* __restrict__ b1,
                                             uint4* __restrict__ wfrag,
                                             float* __restrict__ b1p) {
    int idx = blockIdx.x * 256 + threadIdx.x;
    if (idx < 3072) {
        int q = idx & 3, n = (idx >> 2) & 127, c = idx >> 9;
        int k0 = c * 32 + q * 8;
        float f[8];
#pragma unroll
        for (int j = 0; j < 8; j++) {
            int k = k0 + j;
            f[j] = (k < IN_DIM) ? W1[k * 128 + n] : 0.f;
        }
        uint4 u;
        u.x = pack_bf16(f[0], f[1]);
        u.y = pack_bf16(f[2], f[3]);
        u.z = pack_bf16(f[4], f[5]);
        u.w = pack_bf16(f[6], f[7]);
        wfrag[idx] = u;
    }
    if (blockIdx.x == 0 && threadIdx.x < 128) b1p[threadIdx.x] = b1[pcol(threadIdx.x)];
}

// ---------- x -> bf16, rows padded to 192 (16B-aligned A-fragments) ----------
__global__ __launch_bounds__(256) void xprep(const float* __restrict__ x,
                                             unsigned* __restrict__ xb, int N) {
    int tid = blockIdx.x * 256 + threadIdx.x;
    if (tid >= N * 24) return;
    int row = tid / 24, seg = tid % 24;
    int k0 = seg * 8;
    const float* xr = x + (size_t)row * IN_DIM + k0;
    float f[8];
#pragma unroll
    for (int j = 0; j < 8; j++)
        f[j] = (k0 + j < IN_DIM) ? xr[j] : 0.f;
    uint4 u;
    u.x = pack_bf16(f[0], f[1]);
    u.y = pack_bf16(f[2], f[3]);
    u.z = pack_bf16(f[4], f[5]);
    u.w = pack_bf16(f[6], f[7]);
    *(uint4*)&xb[(size_t)row * 96 + seg * 4] = u;
}

// ---------- GEMM1 via bf16 MFMA, LDS-free ----------
// Wave w owns rows blockIdx*64 + w*16 .. +15, all 128 cols (8 acc tiles).
// A-frag: uint4 from xb (row-local, read once grid-wide).
// B-frag: uint4 from wfrag (identical across blocks -> L1/L2-resident).
// Epilogue: h1p[row*64 + p*16 + l16] = bf16 pair (cols 32p+l16, 32p+16+l16),
// pre-scaled by dinv[row]  (pcol perm layout).
__global__ __launch_bounds__(256) void gemm1_mfma(const uint4* __restrict__ xb,
                                                  const uint4* __restrict__ wfrag,
                                                  const float* __restrict__ dinv,
                                                  unsigned* __restrict__ h1p, int M) {
    const int t = threadIdx.x;
    const int wave = t >> 6;
    const int lane = t & 63;
    const int l16 = lane & 15;
    const int quad = lane >> 4;
    const int rowbase = blockIdx.x * 64 + wave * 16;

    int arow = rowbase + l16;
    if (arow >= M) arow = M - 1;

    f32x4 acc[8];
#pragma unroll
    for (int nt = 0; nt < 8; nt++) acc[nt] = (f32x4){0.f, 0.f, 0.f, 0.f};

#pragma unroll
    for (int c = 0; c < 6; c++) {
        uint4 au = xb[(size_t)arow * 24 + c * 4 + quad];
        bf16x8 a = __builtin_bit_cast(bf16x8, au);
#pragma unroll
        for (int nt = 0; nt < 8; nt++) {
            uint4 bu = wfrag[(size_t)((c * 128 + nt * 16 + l16) * 4 + quad)];
            bf16x8 b = __builtin_bit_cast(bf16x8, bu);
            acc[nt] = __builtin_amdgcn_mfma_f32_16x16x32_bf16(a, b, acc[nt], 0, 0, 0);
        }
    }

#pragma unroll
    for (int r = 0; r < 4; r++) {
        int row = rowbase + quad * 4 + r;
        if (row < M) {
            float s = dinv[row];
#pragma unroll
            for (int p = 0; p < 4; p++) {
                h1p[(size_t)row * 64 + p * 16 + l16] =
                    pack_bf16(acc[2 * p][r] * s, acc[2 * p + 1][r] * s);
            }
        }
    }
}

__device__ inline void acc8(float* a, uint4 u) {
    a[0] += __uint_as_float(u.x << 16);
    a[1] += __uint_as_float(u.x & 0xFFFF0000u);
    a[2] += __uint_as_float(u.y << 16);
    a[3] += __uint_as_float(u.y & 0xFFFF0000u);
    a[4] += __uint_as_float(u.z << 16);
    a[5] += __uint_as_float(u.z & 0xFFFF0000u);
    a[6] += __uint_as_float(u.w << 16);
    a[7] += __uint_as_float(u.w & 0xFFFF0000u);
}

// ---------- GCN gather: quarter-wave (16 lanes) per dst node, bf16 rows ----------
__global__ __launch_bounds__(256) void gcn_gather(const int* __restrict__ offsets,
                                                  const int* __restrict__ csr_src,
                                                  const uint4* __restrict__ h1v,
                                                  const float* __restrict__ dinv,
                                                  const float* __restrict__ b1p,
                                                  float* __restrict__ g, int n) {
    int node = (blockIdx.x * 256 + threadIdx.x) >> 4;
    int lane = threadIdx.x & 15;
    if (node >= n) return;
    int s0 = offsets[node], s1 = offsets[node + 1];

    float a0[8], a1[8], a2[8], a3[8];
#pragma unroll
    for (int i = 0; i < 8; i++) { a0[i] = 0.f; a1[i] = 0.f; a2[i] = 0.f; a3[i] = 0.f; }
    acc8(a0, h1v[(size_t)node * 16 + lane]);   // self loop (pre-scaled)

    int k = s0;
    for (; k + 4 <= s1; k += 4) {
        int r0 = csr_src[k], r1 = csr_src[k + 1], r2 = csr_src[k + 2], r3 = csr_src[k + 3];
        uint4 v0 = h1v[(size_t)r0 * 16 + lane];
        uint4 v1 = h1v[(size_t)r1 * 16 + lane];
        uint4 v2 = h1v[(size_t)r2 * 16 + lane];
        uint4 v3 = h1v[(size_t)r3 * 16 + lane];
        acc8(a0, v0);
        acc8(a1, v1);
        acc8(a2, v2);
        acc8(a3, v3);
    }
    for (; k < s1; k++) {
        int r = csr_src[k];
        acc8(a0, h1v[(size_t)r * 16 + lane]);
    }

    float dc = dinv[node];
    float4 bb0 = ((const float4*)b1p)[lane * 2];
    float4 bb1 = ((const float4*)b1p)[lane * 2 + 1];
    float4 o0, o1;
    o0.x = fmaxf(((a0[0] + a1[0]) + (a2[0] + a3[0])) * dc + bb0.x, 0.f);
    o0.y = fmaxf(((a0[1] + a1[1]) + (a2[1] + a3[1])) * dc + bb0.y, 0.f);
    o0.z = fmaxf(((a0[2] + a1[2]) + (a2[2] + a3[2])) * dc + bb0.z, 0.f);
    o0.w = fmaxf(((a0[3] + a1[3]) + (a2[3] + a3[3])) * dc + bb0.w, 0.f);
    o1.x = fmaxf(((a0[4] + a1[4]) + (a2[4] + a3[4])) * dc + bb1.x, 0.f);
    o1.y = fmaxf(((a0[5] + a1[5]) + (a2[5] + a3[5])) * dc + bb1.y, 0.f);
    o1.z = fmaxf(((a0[6] + a1[6]) + (a2[6] + a3[6])) * dc + bb1.z, 0.f);
    o1.w = fmaxf(((a0[7] + a1[7]) + (a2[7] + a3[7])) * dc + bb1.w, 0.f);
    float4* gv = (float4*)&g[(size_t)node * HID + lane * 8];
    gv[0] = o0;
    gv[1] = o1;
}

// ---------- GEMM2 + fused attention coefficients (A = g in perm layout) ----------
__global__ __launch_bounds__(1024, 4) void gemm2_fused(const float* __restrict__ A,
                                                       const float* __restrict__ B,
                                                       const float* __restrict__ a_src,
                                                       const float* __restrict__ a_dst,
                                                       float* __restrict__ h2,
                                                       float* __restrict__ es,
                                                       float* __restrict__ ed, int M) {
    constexpr int K_ = HID, N_ = OUT_H, TM = 2, TN = 4, TX = 16;
    __shared__ float Bs[K_ * N_];
    const int t = threadIdx.x;
    const int tx = t % TX;
    const int ty = t / TX;
    const int col = tx * TN;
    constexpr int BM = (1024 / TX) * TM;   // 128
    const int row0 = blockIdx.x * BM + ty * TM;

    int rclamp[TM];
#pragma unroll
    for (int r = 0; r < TM; r++) {
        int rr = row0 + r;
        rclamp[r] = rr < M ? rr : (M - 1);
    }

    float acc[TM][TN];
#pragma unroll
    for (int r = 0; r < TM; r++)
#pragma unroll
        for (int c = 0; c < TN; c++) acc[r][c] = 0.f;

    for (int i = t; i < K_ * N_; i += 1024) {
        int j = i >> 6, n2 = i & 63;
        Bs[i] = B[pcol(j) * 64 + n2];
    }
    __syncthreads();

    for (int k = 0; k + 8 <= K_; k += 8) {
        float a[TM][8];
#pragma unroll
        for (int r = 0; r < TM; r++)
#pragma unroll
            for (int kk = 0; kk < 8; kk++)
                a[r][kk] = A[(size_t)rclamp[r] * K_ + k + kk];
#pragma unroll
        for (int kk = 0; kk < 8; kk++) {
            float b[TN];
#pragma unroll
            for (int c = 0; c < TN; c++) b[c] = Bs[(k + kk) * N_ + col + c];
#pragma unroll
            for (int r = 0; r < TM; r++)
#pragma unroll
                for (int c = 0; c < TN; c++)
                    acc[r][c] = fmaf(a[r][kk], b[c], acc[r][c]);
        }
    }

    float asv[TN], adv[TN];
#pragma unroll
    for (int c = 0; c < TN; c++) { asv[c] = a_src[col + c]; adv[c] = a_dst[col + c]; }

#pragma unroll
    for (int r = 0; r < TM; r++) {
        int gr = row0 + r;
        float ps = acc[r][0] * asv[0] + acc[r][1] * asv[1] + acc[r][2] * asv[2] + acc[r][3] * asv[3];
        float pd = acc[r][0] * adv[0] + acc[r][1] * adv[1] + acc[r][2] * adv[2] + acc[r][3] * adv[3];
#pragma unroll
        for (int m = 8; m; m >>= 1) {
            ps += __shfl_xor(ps, m, 16);
            pd += __shfl_xor(pd, m, 16);
        }
        if (gr < M) {
            float4 v = make_float4(acc[r][0], acc[r][1], acc[r][2], acc[r][3]);
            *(float4*)&h2[(size_t)gr * N_ + col] = v;
            if (tx == 0) { es[gr] = ps; ed[gr] = pd; }
        }
    }
}

// ---------- fused GAT: quarter-wave per node, float4 lanes, unnormalized softmax ----------
__global__ __launch_bounds__(256) void gat_fused(const int* __restrict__ offsets,
                                                 const int* __restrict__ csr_src,
                                                 const float4* __restrict__ h2v,
                                                 const float* __restrict__ es,
                                                 const float* __restrict__ ed,
                                                 const float* __restrict__ bg,
                                                 const float* __restrict__ Wfc,
                                                 const float* __restrict__ bfc,
                                                 float* __restrict__ out, int n) {
    int node = (blockIdx.x * 256 + threadIdx.x) >> 4;
    int lane = threadIdx.x & 15;
    if (node >= n) return;
    int s0 = offsets[node], s1 = offsets[node + 1];
    float edc = ed[node];

    float eself = es[node] + edc;
    eself = eself > 0.f ? eself : NSL * eself;
    float x0s = __expf(eself);
    float sA = x0s, sB = 0.f, sC = 0.f, sD = 0.f;
    float4 hs = h2v[(size_t)node * 16 + lane];
    float4 aA = make_float4(x0s * hs.x, x0s * hs.y, x0s * hs.z, x0s * hs.w);
    float4 aB = make_float4(0.f, 0.f, 0.f, 0.f), aC = aB, aD = aB;

    int k = s0;
    for (; k + 4 <= s1; k += 4) {
        int r0 = csr_src[k], r1 = csr_src[k + 1], r2 = csr_src[k + 2], r3 = csr_src[k + 3];
        float e0 = es[r0] + edc, e1 = es[r1] + edc, e2 = es[r2] + edc, e3 = es[r3] + edc;
        e0 = e0 > 0.f ? e0 : NSL * e0;
        e1 = e1 > 0.f ? e1 : NSL * e1;
        e2 = e2 > 0.f ? e2 : NSL * e2;
        e3 = e3 > 0.f ? e3 : NSL * e3;
        float x0 = __expf(e0), x1 = __expf(e1), x2 = __expf(e2), x3 = __expf(e3);
        float4 v0 = h2v[(size_t)r0 * 16 + lane];
        float4 v1 = h2v[(size_t)r1 * 16 + lane];
        float4 v2 = h2v[(size_t)r2 * 16 + lane];
        float4 v3 = h2v[(size_t)r3 * 16 + lane];
        sA += x0; sB += x1; sC += x2; sD += x3;
        aA.x = fmaf(x0, v0.x, aA.x); aA.y = fmaf(x0, v0.y, aA.y);
        aA.z = fmaf(x0, v0.z, aA.z); aA.w = fmaf(x0, v0.w, aA.w);
        aB.x = fmaf(x1, v1.x, aB.x); aB.y = fmaf(x1, v1.y, aB.y);
        aB.z = fmaf(x1, v1.z, aB.z); aB.w = fmaf(x1, v1.w, aB.w);
        aC.x = fmaf(x2, v2.x, aC.x); aC.y = fmaf(x2, v2.y, aC.y);
        aC.z = fmaf(x2, v2.z, aC.z); aC.w = fmaf(x2, v2.w, aC.w);
        aD.x = fmaf(x3, v3.x, aD.x); aD.y = fmaf(x3, v3.y, aD.y);
        aD.z = fmaf(x3, v3.z, aD.z); aD.w = fmaf(x3, v3.w, aD.w);
    }
    for (; k < s1; k++) {
        int r = csr_src[k];
        float e = es[r] + edc;
        e = e > 0.f ? e : NSL * e;
        float xv = __expf(e);
        float4 hv = h2v[(size_t)r * 16 + lane];
        sA += xv;
        aA.x = fmaf(xv, hv.x, aA.x); aA.y = fmaf(xv, hv.y, aA.y);
        aA.z = fmaf(xv, hv.z, aA.z); aA.w = fmaf(xv, hv.w, aA.w);
    }
    float s = (sA + sB) + (sC + sD);
    float rcp = 1.0f / s;
    float4 bb = ((const float4*)bg)[lane];
    float ox = fmaxf(((aA.x + aB.x) + (aC.x + aD.x)) * rcp + bb.x, 0.f);
    float oy = fmaxf(((aA.y + aB.y) + (aC.y + aD.y)) * rcp + bb.y, 0.f);
    float oz = fmaxf(((aA.z + aB.z) + (aC.z + aD.z)) * rcp + bb.z, 0.f);
    float ow = fmaxf(((aA.w + aB.w) + (aC.w + aD.w)) * rcp + bb.w, 0.f);
    float4 w0 = ((const float4*)Wfc)[lane * 2];
    float4 w1 = ((const float4*)Wfc)[lane * 2 + 1];
    float p0 = ox * w0.x + oy * w0.z + oz * w1.x + ow * w1.z;
    float p1 = ox * w0.y + oy * w0.w + oz * w1.y + ow * w1.w;
#pragma unroll
    for (int m = 8; m; m >>= 1) {
        p0 += __shfl_xor(p0, m, 16);
        p1 += __shfl_xor(p1, m, 16);
    }
    if (lane == 0) {
        out[(size_t)node * 2 + 0] = p0 + bfc[0];
        out[(size_t)node * 2 + 1] = p1 + bfc[1];
    }
}

extern "C" void kernel_launch(void* const* d_in, const int* in_sizes, int n_in,
                              void* d_out, int out_size, void* d_ws, size_t ws_size,
                              hipStream_t stream) {
    const float* x     = (const float*)d_in[0];
    const int*   ei    = (const int*)d_in[1];
    const float* W1    = (const float*)d_in[2];
    const float* b1    = (const float*)d_in[3];
    const float* Wg    = (const float*)d_in[4];
    const float* a_src = (const float*)d_in[5];
    const float* a_dst = (const float*)d_in[6];
    const float* bg    = (const float*)d_in[7];
    const float* Wfc   = (const float*)d_in[8];
    const float* bfc   = (const float*)d_in[9];
    float* out = (float*)d_out;

    const int N = in_sizes[0] / IN_DIM;
    const int E = in_sizes[1] / 2;
    const int* rowi = ei;
    const int* coli = ei + E;
    const int ncb = (N + 255) >> 8;            // coarse buckets of 256 nodes

    auto alignup = [](char* p) { return (char*)(((uintptr_t)p + 15) & ~(uintptr_t)15); };

    // workspace layout, ~197N + 2E words ≈ 92 MB (xb aliases g)
    char* wsb = (char*)d_ws;
    int*   degi    = (int*)wsb;                         // N
    int*   offsets = degi + N;                          // N+8
    float* dinv    = (float*)(offsets + N + 8);         // N
    float* es      = dinv + N;                          // N
    float* ed      = es + N;                            // N
    int*   ghist   = (int*)(ed + N);                    // NCB_MAX
    int*   cstart  = ghist + NCB_MAX;                   // NCB_MAX+2
    int*   gcursor = cstart + NCB_MAX + 2;              // NCB_MAX
    int*   bsums   = gcursor + NCB_MAX;                 // 512
    float* b1p     = (float*)(bsums + 512);             // 128
    uint4* wfrag   = (uint4*)alignup((char*)(b1p + 128));   // 3072 uint4 (48 KB)
    int*   csr_src = (int*)(wfrag + 3072);              // E
    unsigned* ebuf = (unsigned*)(csr_src + E);          // E (packed row<<8|local)
    unsigned* h1p  = (unsigned*)alignup((char*)(ebuf + E)); // N*64 words (bf16 pairs, perm)
    float* g       = (float*)alignup((char*)(h1p + (size_t)N * 64)); // N*128 (perm layout)
    unsigned* xb   = (unsigned*)g;                      // alias: xb dead before g is written
    float* h2      = (float*)h1p;                       // alias: h1p dead after gcn_gather

    hipMemsetAsync(ghist, 0, NCB_MAX * 4, stream);

    const int nbE = (E + EPB - 1) / EPB;
    const int nbScan = (N + SCAN_B - 1) / SCAN_B;

    // 1) CSR build: coarse hist -> scan -> privatized scatter -> fine counts
    //    -> N-scan -> block-local fill
    chist<<<nbE, 256, 0, stream>>>(coli, E, ghist, ncb);
    cscan<<<1, NCB_MAX, 0, stream>>>(ghist, cstart, gcursor, ncb, E);
    pass1_scatter<<<nbE, 256, 0, stream>>>(rowi, coli, E, gcursor, ebuf, ncb);
    pass2_count<<<ncb, 256, 0, stream>>>(ebuf, cstart, degi, N);
    scan_block<<<nbScan, SCAN_B, 0, stream>>>(degi, offsets, bsums, N);
    scan_bsums<<<1, 256, 0, stream>>>(bsums, nbScan);
    scan_finalize<<<(N + 256) / 256, 256, 0, stream>>>(degi, bsums, offsets, dinv, N, E);
    pass2_fill<<<ncb, 256, 0, stream>>>(ebuf, cstart, offsets, csr_src, N);

    // 2) operand prep: W1 -> bf16 fragments (+ permuted bias); x -> bf16 padded rows
    wprep<<<12, 256, 0, stream>>>(W1, b1, wfrag, b1p);
    xprep<<<(N * 24 + 255) / 256, 256, 0, stream>>>(x, xb, N);

    // 3) h1p = perm-packed bf16((x @ W1) * dinv[row]) via LDS-free MFMA
    gemm1_mfma<<<(N + 63) / 64, 256, 0, stream>>>((const uint4*)xb, wfrag, dinv, h1p, N);

    // 4) GCN gather (pure-sum aggregation, fused dinv[col]*, bias, relu)
    gcn_gather<<<(N + 15) / 16, 256, 0, stream>>>(offsets, csr_src, (const uint4*)h1p,
                                                  dinv, b1p, g, N);

    // 5) h2 = g @ Wg with fused es/ed epilogue (un-permutes via Wg staging)
    gemm2_fused<<<(N + 127) / 128, 1024, 0, stream>>>(g, Wg, a_src, a_dst, h2, es, ed, N);

    // 6) fused GAT: unnormalized-softmax gather + relu + final FC
    gat_fused<<<(N + 15) / 16, 256, 0, stream>>>(offsets, csr_src, (const float4*)h2,
                                                 es, ed, bg, Wfc, bfc, out, N);
}

// Round 10
// 387.055 us; speedup vs baseline: 1.6537x; 1.1343x over previous
//
#include <hip/hip_runtime.h>
#include <math.h>

#define NSL 0.2f   // leaky relu negative slope
#define IN_DIM 165
#define HID 128
#define OUT_H 64
#define SCAN_B 512  // elements per scan block
#define NCB_MAX 512 // max coarse buckets (N <= 131072)
#define EPB 4096    // edges per pass1 block

typedef __attribute__((ext_vector_type(8))) short bf16x8;
typedef __attribute__((ext_vector_type(4))) float f32x4;

// ---------- bf16 pack (round-to-nearest-even) ----------
__device__ inline unsigned pack_bf16(float a, float b) {
    unsigned ua = __float_as_uint(a);
    ua += 0x7FFFu + ((ua >> 16) & 1u);
    unsigned ub = __float_as_uint(b);
    ub += 0x7FFFu + ((ub >> 16) & 1u);
    return (ua >> 16) | (ub & 0xFFFF0000u);
}

// column permutation of the packed layouts: stored bf16 index i -> original col.
// Works for both 128-col (h1/g) and 64-col (h2) matrices.
__device__ __host__ inline int pcol(int i) {
    int j = i >> 1, odd = i & 1;
    return 32 * (j >> 4) + (j & 15) + 16 * odd;
}

// ---------- coarse histogram (LDS-privatized) ----------
__global__ __launch_bounds__(256) void chist(const int* __restrict__ coli, int E,
                                             int* __restrict__ ghist, int ncb) {
    __shared__ int h[NCB_MAX];
    for (int i = threadIdx.x; i < ncb; i += 256) h[i] = 0;
    __syncthreads();
    int e0 = blockIdx.x * EPB;
    int e1 = min(e0 + EPB, E);
    for (int e = e0 + threadIdx.x; e < e1; e += 256)
        atomicAdd(&h[coli[e] >> 8], 1);
    __syncthreads();
    for (int i = threadIdx.x; i < ncb; i += 256)
        if (h[i]) atomicAdd(&ghist[i], h[i]);
}

// ---------- 1-block scan of coarse histogram -> cstart, gcursor ----------
__global__ __launch_bounds__(NCB_MAX) void cscan(const int* __restrict__ ghist,
                                                 int* __restrict__ cstart,
                                                 int* __restrict__ gcursor,
                                                 int ncb, int E) {
    __shared__ int tmp[NCB_MAX];
    int tid = threadIdx.x;
    int v = (tid < ncb) ? ghist[tid] : 0;
    tmp[tid] = v;
    __syncthreads();
    for (int off = 1; off < NCB_MAX; off <<= 1) {
        int t = (tid >= off) ? tmp[tid - off] : 0;
        __syncthreads();
        tmp[tid] += t;
        __syncthreads();
    }
    if (tid < ncb) {
        int excl = tmp[tid] - v;
        cstart[tid] = excl;
        gcursor[tid] = excl;
    }
    if (tid == ncb - 1) cstart[ncb] = E;
}

// ---------- pass1: block-privatized scatter into coarse buckets ----------
// ebuf value = (row << 8) | (col & 255)   (requires N < 2^24)
__global__ __launch_bounds__(256) void pass1_scatter(const int* __restrict__ rowi,
                                                     const int* __restrict__ coli, int E,
                                                     int* __restrict__ gcursor,
                                                     unsigned* __restrict__ ebuf, int ncb) {
    __shared__ int hist[NCB_MAX];
    __shared__ int base[NCB_MAX];
    int e0 = blockIdx.x * EPB;
    int e1 = min(e0 + EPB, E);
    for (int i = threadIdx.x; i < ncb; i += 256) hist[i] = 0;
    __syncthreads();
    for (int e = e0 + threadIdx.x; e < e1; e += 256)
        atomicAdd(&hist[coli[e] >> 8], 1);
    __syncthreads();
    for (int i = threadIdx.x; i < ncb; i += 256) {
        int h = hist[i];
        base[i] = h ? atomicAdd(&gcursor[i], h) : 0;
        hist[i] = 0;
    }
    __syncthreads();
    for (int e = e0 + threadIdx.x; e < e1; e += 256) {
        int c = coli[e];
        int cb = c >> 8;
        int rank = atomicAdd(&hist[cb], 1);
        ebuf[base[cb] + rank] = ((unsigned)rowi[e] << 8) | (unsigned)(c & 255);
    }
}

// ---------- pass2a: per-bucket fine-degree count -> degi (coalesced write) ----------
__global__ __launch_bounds__(256) void pass2_count(const unsigned* __restrict__ ebuf,
                                                   const int* __restrict__ cstart,
                                                   int* __restrict__ degi, int n) {
    __shared__ int cnt[256];
    int cb = blockIdx.x;
    cnt[threadIdx.x] = 0;
    __syncthreads();
    int s = cstart[cb], e1 = cstart[cb + 1];
    for (int e = s + threadIdx.x; e < e1; e += 256)
        atomicAdd(&cnt[ebuf[e] & 255u], 1);
    __syncthreads();
    int node = (cb << 8) + threadIdx.x;
    if (node < n) degi[node] = cnt[threadIdx.x];
}

// ---------- block-level inclusive scan (512 elems / block) ----------
__global__ __launch_bounds__(SCAN_B) void scan_block(const int* __restrict__ degi,
                                                     int* __restrict__ incl,
                                                     int* __restrict__ bsums, int n) {
    __shared__ int tmp[SCAN_B];
    int tid = threadIdx.x;
    int gid = blockIdx.x * SCAN_B + tid;
    int v = (gid < n) ? degi[gid] : 0;
    tmp[tid] = v;
    __syncthreads();
    for (int off = 1; off < SCAN_B; off <<= 1) {
        int t = (tid >= off) ? tmp[tid - off] : 0;
        __syncthreads();
        tmp[tid] += t;
        __syncthreads();
    }
    if (gid < n) incl[gid] = tmp[tid];
    if (tid == SCAN_B - 1) bsums[blockIdx.x] = tmp[tid];
}

// ---------- single-block exclusive scan of block sums (nb <= 256) ----------
__global__ __launch_bounds__(256) void scan_bsums(int* __restrict__ bsums, int nb) {
    __shared__ int tmp[256];
    int tid = threadIdx.x;
    int v = (tid < nb) ? bsums[tid] : 0;
    tmp[tid] = v;
    __syncthreads();
    for (int off = 1; off < 256; off <<= 1) {
        int t = (tid >= off) ? tmp[tid - off] : 0;
        __syncthreads();
        tmp[tid] += t;
        __syncthreads();
    }
    if (tid < nb) bsums[tid] = tmp[tid] - v;   // exclusive
}

// ---------- finalize: exclusive offsets, dinv; offsets[n]=E ----------
__global__ __launch_bounds__(256) void scan_finalize(const int* __restrict__ degi,
                                                     const int* __restrict__ bsums,
                                                     int* __restrict__ offsets,  // holds incl on entry
                                                     float* __restrict__ dinv,
                                                     int n, int E) {
    int gid = blockIdx.x * 256 + threadIdx.x;
    if (gid < n) {
        int excl = offsets[gid] - degi[gid] + bsums[gid >> 9];
        offsets[gid] = excl;
        dinv[gid] = rsqrtf((float)degi[gid] + 1.0f);   // +1 = self loop
    } else if (gid == n) {
        offsets[n] = E;
    }
}

// ---------- pass2b: per-bucket rank + fill csr_src (block-exclusive window) ----------
__global__ __launch_bounds__(256) void pass2_fill(const unsigned* __restrict__ ebuf,
                                                  const int* __restrict__ cstart,
                                                  const int* __restrict__ offsets,
                                                  int* __restrict__ csr_src, int n) {
    __shared__ int cnt[256];
    __shared__ int offs[256];
    int cb = blockIdx.x;
    int node = (cb << 8) + threadIdx.x;
    cnt[threadIdx.x] = 0;
    offs[threadIdx.x] = (node < n) ? offsets[node] : 0;
    __syncthreads();
    int s = cstart[cb], e1 = cstart[cb + 1];
    for (int e = s + threadIdx.x; e < e1; e += 256) {
        unsigned v = ebuf[e];
        int local = v & 255u;
        int rank = atomicAdd(&cnt[local], 1);
        csr_src[offs[local] + rank] = (int)(v >> 8);
    }
}

// ---------- W1 -> bf16 B-fragment layout (48 KB) + permuted bias ----------
__global__ __launch_bounds__(256) void wprep(const float* __restrict__ W1,
                                             const float* __restrict__ b1,
                                             uint4* __restrict__ wfrag,
                                             float* __restrict__ b1p) {
    int idx = blockIdx.x * 256 + threadIdx.x;
    if (idx < 3072) {
        int q = idx & 3, n = (idx >> 2) & 127, c = idx >> 9;
        int k0 = c * 32 + q * 8;
        float f[8];
#pragma unroll
        for (int j = 0; j < 8; j++) {
            int k = k0 + j;
            f[j] = (k < IN_DIM) ? W1[k * 128 + n] : 0.f;
        }
        uint4 u;
        u.x = pack_bf16(f[0], f[1]);
        u.y = pack_bf16(f[2], f[3]);
        u.z = pack_bf16(f[4], f[5]);
        u.w = pack_bf16(f[6], f[7]);
        wfrag[idx] = u;
    }
    if (blockIdx.x == 0 && threadIdx.x < 128) b1p[threadIdx.x] = b1[pcol(threadIdx.x)];
}

// ---------- Wg -> bf16 fragments in stored-k order (16 KB) + permuted bg/Wfc ----------
// wg2frag[(c*64 + n)*4 + q] = 8 bf16 of Wg[pcol(c*32+q*8+j)][n]
__global__ __launch_bounds__(256) void wprep2(const float* __restrict__ Wg,
                                              const float* __restrict__ bg,
                                              const float* __restrict__ Wfc,
                                              uint4* __restrict__ wg2frag,
                                              float* __restrict__ bgp,
                                              float2* __restrict__ wfcp) {
    int idx = blockIdx.x * 256 + threadIdx.x;
    if (idx < 1024) {
        int q = idx & 3, n = (idx >> 2) & 63, c = idx >> 8;
        float f[8];
#pragma unroll
        for (int j = 0; j < 8; j++) {
            int ks = c * 32 + q * 8 + j;       // stored k index
            f[j] = Wg[pcol(ks) * 64 + n];      // orig k = pcol(ks)
        }
        uint4 u;
        u.x = pack_bf16(f[0], f[1]);
        u.y = pack_bf16(f[2], f[3]);
        u.z = pack_bf16(f[4], f[5]);
        u.w = pack_bf16(f[6], f[7]);
        wg2frag[idx] = u;
    }
    if (blockIdx.x == 0 && threadIdx.x < 64) {
        int i = threadIdx.x;
        int o = pcol(i);
        bgp[i] = bg[o];
        wfcp[i] = make_float2(Wfc[o * 2], Wfc[o * 2 + 1]);
    }
}

// ---------- x -> bf16, rows padded to 192 (16B-aligned A-fragments) ----------
__global__ __launch_bounds__(256) void xprep(const float* __restrict__ x,
                                             unsigned* __restrict__ xb, int N) {
    int tid = blockIdx.x * 256 + threadIdx.x;
    if (tid >= N * 24) return;
    int row = tid / 24, seg = tid % 24;
    int k0 = seg * 8;
    const float* xr = x + (size_t)row * IN_DIM + k0;
    float f[8];
#pragma unroll
    for (int j = 0; j < 8; j++)
        f[j] = (k0 + j < IN_DIM) ? xr[j] : 0.f;
    uint4 u;
    u.x = pack_bf16(f[0], f[1]);
    u.y = pack_bf16(f[2], f[3]);
    u.z = pack_bf16(f[4], f[5]);
    u.w = pack_bf16(f[6], f[7]);
    *(uint4*)&xb[(size_t)row * 96 + seg * 4] = u;
}

// ---------- GEMM1 via bf16 MFMA, LDS-free ----------
__global__ __launch_bounds__(256) void gemm1_mfma(const uint4* __restrict__ xb,
                                                  const uint4* __restrict__ wfrag,
                                                  const float* __restrict__ dinv,
                                                  unsigned* __restrict__ h1p, int M) {
    const int t = threadIdx.x;
    const int wave = t >> 6;
    const int lane = t & 63;
    const int l16 = lane & 15;
    const int quad = lane >> 4;
    const int rowbase = blockIdx.x * 64 + wave * 16;

    int arow = rowbase + l16;
    if (arow >= M) arow = M - 1;

    f32x4 acc[8];
#pragma unroll
    for (int nt = 0; nt < 8; nt++) acc[nt] = (f32x4){0.f, 0.f, 0.f, 0.f};

#pragma unroll
    for (int c = 0; c < 6; c++) {
        uint4 au = xb[(size_t)arow * 24 + c * 4 + quad];
        bf16x8 a = __builtin_bit_cast(bf16x8, au);
#pragma unroll
        for (int nt = 0; nt < 8; nt++) {
            uint4 bu = wfrag[(size_t)((c * 128 + nt * 16 + l16) * 4 + quad)];
            bf16x8 b = __builtin_bit_cast(bf16x8, bu);
            acc[nt] = __builtin_amdgcn_mfma_f32_16x16x32_bf16(a, b, acc[nt], 0, 0, 0);
        }
    }

#pragma unroll
    for (int r = 0; r < 4; r++) {
        int row = rowbase + quad * 4 + r;
        if (row < M) {
            float s = dinv[row];
#pragma unroll
            for (int p = 0; p < 4; p++) {
                h1p[(size_t)row * 64 + p * 16 + l16] =
                    pack_bf16(acc[2 * p][r] * s, acc[2 * p + 1][r] * s);
            }
        }
    }
}

__device__ inline void acc8(float* a, uint4 u) {
    a[0] += __uint_as_float(u.x << 16);
    a[1] += __uint_as_float(u.x & 0xFFFF0000u);
    a[2] += __uint_as_float(u.y << 16);
    a[3] += __uint_as_float(u.y & 0xFFFF0000u);
    a[4] += __uint_as_float(u.z << 16);
    a[5] += __uint_as_float(u.z & 0xFFFF0000u);
    a[6] += __uint_as_float(u.w << 16);
    a[7] += __uint_as_float(u.w & 0xFFFF0000u);
}

__device__ inline void fma8(float* a, uint4 u, float w) {
    a[0] = fmaf(__uint_as_float(u.x << 16), w, a[0]);
    a[1] = fmaf(__uint_as_float(u.x & 0xFFFF0000u), w, a[1]);
    a[2] = fmaf(__uint_as_float(u.y << 16), w, a[2]);
    a[3] = fmaf(__uint_as_float(u.y & 0xFFFF0000u), w, a[3]);
    a[4] = fmaf(__uint_as_float(u.z << 16), w, a[4]);
    a[5] = fmaf(__uint_as_float(u.z & 0xFFFF0000u), w, a[5]);
    a[6] = fmaf(__uint_as_float(u.w << 16), w, a[6]);
    a[7] = fmaf(__uint_as_float(u.w & 0xFFFF0000u), w, a[7]);
}

// ---------- GCN gather: quarter-wave per dst node, bf16 in, bf16 out ----------
__global__ __launch_bounds__(256) void gcn_gather(const int* __restrict__ offsets,
                                                  const int* __restrict__ csr_src,
                                                  const uint4* __restrict__ h1v,
                                                  const float* __restrict__ dinv,
                                                  const float* __restrict__ b1p,
                                                  uint4* __restrict__ gb, int n) {
    int node = (blockIdx.x * 256 + threadIdx.x) >> 4;
    int lane = threadIdx.x & 15;
    if (node >= n) return;
    int s0 = offsets[node], s1 = offsets[node + 1];

    float a0[8], a1[8], a2[8], a3[8];
#pragma unroll
    for (int i = 0; i < 8; i++) { a0[i] = 0.f; a1[i] = 0.f; a2[i] = 0.f; a3[i] = 0.f; }
    acc8(a0, h1v[(size_t)node * 16 + lane]);   // self loop (pre-scaled)

    int k = s0;
    for (; k + 4 <= s1; k += 4) {
        int r0 = csr_src[k], r1 = csr_src[k + 1], r2 = csr_src[k + 2], r3 = csr_src[k + 3];
        uint4 v0 = h1v[(size_t)r0 * 16 + lane];
        uint4 v1 = h1v[(size_t)r1 * 16 + lane];
        uint4 v2 = h1v[(size_t)r2 * 16 + lane];
        uint4 v3 = h1v[(size_t)r3 * 16 + lane];
        acc8(a0, v0);
        acc8(a1, v1);
        acc8(a2, v2);
        acc8(a3, v3);
    }
    for (; k < s1; k++) {
        int r = csr_src[k];
        acc8(a0, h1v[(size_t)r * 16 + lane]);
    }

    float dc = dinv[node];
    float4 bb0 = ((const float4*)b1p)[lane * 2];
    float4 bb1 = ((const float4*)b1p)[lane * 2 + 1];
    float o[8];
    o[0] = fmaxf(((a0[0] + a1[0]) + (a2[0] + a3[0])) * dc + bb0.x, 0.f);
    o[1] = fmaxf(((a0[1] + a1[1]) + (a2[1] + a3[1])) * dc + bb0.y, 0.f);
    o[2] = fmaxf(((a0[2] + a1[2]) + (a2[2] + a3[2])) * dc + bb0.z, 0.f);
    o[3] = fmaxf(((a0[3] + a1[3]) + (a2[3] + a3[3])) * dc + bb0.w, 0.f);
    o[4] = fmaxf(((a0[4] + a1[4]) + (a2[4] + a3[4])) * dc + bb1.x, 0.f);
    o[5] = fmaxf(((a0[5] + a1[5]) + (a2[5] + a3[5])) * dc + bb1.y, 0.f);
    o[6] = fmaxf(((a0[6] + a1[6]) + (a2[6] + a3[6])) * dc + bb1.z, 0.f);
    o[7] = fmaxf(((a0[7] + a1[7]) + (a2[7] + a3[7])) * dc + bb1.w, 0.f);
    uint4 pk;
    pk.x = pack_bf16(o[0], o[1]);
    pk.y = pack_bf16(o[2], o[3]);
    pk.z = pack_bf16(o[4], o[5]);
    pk.w = pack_bf16(o[6], o[7]);
    gb[(size_t)node * 16 + lane] = pk;
}

// ---------- GEMM2 via bf16 MFMA, LDS-free; fused es/ed; bf16 h2 out ----------
__global__ __launch_bounds__(256) void gemm2_mfma(const uint4* __restrict__ gb4,
                                                  const uint4* __restrict__ wg2frag,
                                                  const float* __restrict__ a_src,
                                                  const float* __restrict__ a_dst,
                                                  unsigned* __restrict__ h2b,
                                                  float* __restrict__ es,
                                                  float* __restrict__ ed, int M) {
    const int t = threadIdx.x;
    const int wave = t >> 6;
    const int lane = t & 63;
    const int l16 = lane & 15;
    const int quad = lane >> 4;
    const int rowbase = blockIdx.x * 64 + wave * 16;

    int arow = rowbase + l16;
    if (arow >= M) arow = M - 1;

    f32x4 acc[4];
#pragma unroll
    for (int nt = 0; nt < 4; nt++) acc[nt] = (f32x4){0.f, 0.f, 0.f, 0.f};

#pragma unroll
    for (int c = 0; c < 4; c++) {
        uint4 au = gb4[(size_t)arow * 16 + c * 4 + quad];
        bf16x8 a = __builtin_bit_cast(bf16x8, au);
#pragma unroll
        for (int nt = 0; nt < 4; nt++) {
            uint4 bu = wg2frag[(size_t)((c * 64 + nt * 16 + l16) * 4 + quad)];
            bf16x8 b = __builtin_bit_cast(bf16x8, bu);
            acc[nt] = __builtin_amdgcn_mfma_f32_16x16x32_bf16(a, b, acc[nt], 0, 0, 0);
        }
    }

    float as0 = a_src[l16], as1 = a_src[16 + l16], as2 = a_src[32 + l16], as3 = a_src[48 + l16];
    float ad0 = a_dst[l16], ad1 = a_dst[16 + l16], ad2 = a_dst[32 + l16], ad3 = a_dst[48 + l16];

#pragma unroll
    for (int r = 0; r < 4; r++) {
        int row = rowbase + quad * 4 + r;
        float ps = acc[0][r] * as0 + acc[1][r] * as1 + acc[2][r] * as2 + acc[3][r] * as3;
        float pd = acc[0][r] * ad0 + acc[1][r] * ad1 + acc[2][r] * ad2 + acc[3][r] * ad3;
#pragma unroll
        for (int m = 8; m; m >>= 1) {
            ps += __shfl_xor(ps, m, 16);
            pd += __shfl_xor(pd, m, 16);
        }
        if (row < M) {
            h2b[(size_t)row * 32 + l16]      = pack_bf16(acc[0][r], acc[1][r]);
            h2b[(size_t)row * 32 + 16 + l16] = pack_bf16(acc[2][r], acc[3][r]);
            if (l16 == 0) { es[row] = ps; ed[row] = pd; }
        }
    }
}

// ---------- fused GAT: 8 lanes per node, bf16 h2 rows, unnormalized softmax ----------
__global__ __launch_bounds__(256) void gat_fused(const int* __restrict__ offsets,
                                                 const int* __restrict__ csr_src,
                                                 const uint4* __restrict__ h2v,  // row = 8 uint4
                                                 const float* __restrict__ es,
                                                 const float* __restrict__ ed,
                                                 const float* __restrict__ bgp,
                                                 const float2* __restrict__ wfcp,
                                                 const float* __restrict__ bfc,
                                                 float* __restrict__ out, int n) {
    int node = (blockIdx.x * 256 + threadIdx.x) >> 3;
    int lane = threadIdx.x & 7;
    if (node >= n) return;
    int s0 = offsets[node], s1 = offsets[node + 1];
    float edc = ed[node];

    float eself = es[node] + edc;
    eself = eself > 0.f ? eself : NSL * eself;
    float x0s = __expf(eself);
    float sA = x0s, sB = 0.f, sC = 0.f, sD = 0.f;
    float aA[8], aB[8], aC[8], aD[8];
#pragma unroll
    for (int i = 0; i < 8; i++) { aA[i] = 0.f; aB[i] = 0.f; aC[i] = 0.f; aD[i] = 0.f; }
    fma8(aA, h2v[(size_t)node * 8 + lane], x0s);

    int k = s0;
    for (; k + 4 <= s1; k += 4) {
        int r0 = csr_src[k], r1 = csr_src[k + 1], r2 = csr_src[k + 2], r3 = csr_src[k + 3];
        float e0 = es[r0] + edc, e1 = es[r1] + edc, e2 = es[r2] + edc, e3 = es[r3] + edc;
        e0 = e0 > 0.f ? e0 : NSL * e0;
        e1 = e1 > 0.f ? e1 : NSL * e1;
        e2 = e2 > 0.f ? e2 : NSL * e2;
        e3 = e3 > 0.f ? e3 : NSL * e3;
        float x0 = __expf(e0), x1 = __expf(e1), x2 = __expf(e2), x3 = __expf(e3);
        uint4 v0 = h2v[(size_t)r0 * 8 + lane];
        uint4 v1 = h2v[(size_t)r1 * 8 + lane];
        uint4 v2 = h2v[(size_t)r2 * 8 + lane];
        uint4 v3 = h2v[(size_t)r3 * 8 + lane];
        sA += x0; sB += x1; sC += x2; sD += x3;
        fma8(aA, v0, x0);
        fma8(aB, v1, x1);
        fma8(aC, v2, x2);
        fma8(aD, v3, x3);
    }
    for (; k < s1; k++) {
        int r = csr_src[k];
        float e = es[r] + edc;
        e = e > 0.f ? e : NSL * e;
        float xv = __expf(e);
        sA += xv;
        fma8(aA, h2v[(size_t)r * 8 + lane], xv);
    }
    float s = (sA + sB) + (sC + sD);
    float rcp = 1.0f / s;
    float4 b0 = ((const float4*)bgp)[lane * 2];
    float4 b1 = ((const float4*)bgp)[lane * 2 + 1];
    float o[8];
    o[0] = fmaxf(((aA[0] + aB[0]) + (aC[0] + aD[0])) * rcp + b0.x, 0.f);
    o[1] = fmaxf(((aA[1] + aB[1]) + (aC[1] + aD[1])) * rcp + b0.y, 0.f);
    o[2] = fmaxf(((aA[2] + aB[2]) + (aC[2] + aD[2])) * rcp + b0.z, 0.f);
    o[3] = fmaxf(((aA[3] + aB[3]) + (aC[3] + aD[3])) * rcp + b0.w, 0.f);
    o[4] = fmaxf(((aA[4] + aB[4]) + (aC[4] + aD[4])) * rcp + b1.x, 0.f);
    o[5] = fmaxf(((aA[5] + aB[5]) + (aC[5] + aD[5])) * rcp + b1.y, 0.f);
    o[6] = fmaxf(((aA[6] + aB[6]) + (aC[6] + aD[6])) * rcp + b1.z, 0.f);
    o[7] = fmaxf(((aA[7] + aB[7]) + (aC[7] + aD[7])) * rcp + b1.w, 0.f);

    float p0 = 0.f, p1 = 0.f;
#pragma unroll
    for (int m2 = 0; m2 < 4; m2++) {
        float4 w = ((const float4*)wfcp)[lane * 4 + m2];
        p0 += o[2 * m2] * w.x + o[2 * m2 + 1] * w.z;
        p1 += o[2 * m2] * w.y + o[2 * m2 + 1] * w.w;
    }
#pragma unroll
    for (int m = 4; m; m >>= 1) {
        p0 += __shfl_xor(p0, m, 8);
        p1 += __shfl_xor(p1, m, 8);
    }
    if (lane == 0) {
        out[(size_t)node * 2 + 0] = p0 + bfc[0];
        out[(size_t)node * 2 + 1] = p1 + bfc[1];
    }
}

extern "C" void kernel_launch(void* const* d_in, const int* in_sizes, int n_in,
                              void* d_out, int out_size, void* d_ws, size_t ws_size,
                              hipStream_t stream) {
    const float* x     = (const float*)d_in[0];
    const int*   ei    = (const int*)d_in[1];
    const float* W1    = (const float*)d_in[2];
    const float* b1    = (const float*)d_in[3];
    const float* Wg    = (const float*)d_in[4];
    const float* a_src = (const float*)d_in[5];
    const float* a_dst = (const float*)d_in[6];
    const float* bg    = (const float*)d_in[7];
    const float* Wfc   = (const float*)d_in[8];
    const float* bfc   = (const float*)d_in[9];
    float* out = (float*)d_out;

    const int N = in_sizes[0] / IN_DIM;
    const int E = in_sizes[1] / 2;
    const int* rowi = ei;
    const int* coli = ei + E;
    const int ncb = (N + 255) >> 8;            // coarse buckets of 256 nodes

    auto alignup = [](char* p) { return (char*)(((uintptr_t)p + 15) & ~(uintptr_t)15); };

    // workspace layout, ~165N + 2E words ≈ 79 MB
    char* wsb = (char*)d_ws;
    int*   degi    = (int*)wsb;                         // N
    int*   offsets = degi + N;                          // N+8
    float* dinv    = (float*)(offsets + N + 8);         // N
    float* es      = dinv + N;                          // N
    float* ed      = es + N;                            // N
    int*   ghist   = (int*)(ed + N);                    // NCB_MAX
    int*   cstart  = ghist + NCB_MAX;                   // NCB_MAX+2
    int*   gcursor = cstart + NCB_MAX + 2;              // NCB_MAX
    int*   bsums   = gcursor + NCB_MAX;                 // 512
    float* b1p     = (float*)(bsums + 512);             // 128
    float* bgp     = b1p + 128;                         // 64
    float2* wfcp   = (float2*)(bgp + 64);               // 64 float2
    uint4* wfrag   = (uint4*)alignup((char*)(wfcp + 64));   // 3072 uint4 (48 KB)
    uint4* wg2frag = wfrag + 3072;                      // 1024 uint4 (16 KB)
    int*   csr_src = (int*)(wg2frag + 1024);            // E
    unsigned* ebuf = (unsigned*)(csr_src + E);          // E (packed row<<8|local)
    unsigned* h1p  = (unsigned*)alignup((char*)(ebuf + E)); // N*64 words (bf16 pairs, perm)
    unsigned* xgb  = (unsigned*)alignup((char*)(h1p + (size_t)N * 64)); // N*96 words
    unsigned* xb   = xgb;                               // xprep/gemm1 input
    uint4* gb      = (uint4*)xgb;                       // alias: xb dead after gemm1
    unsigned* h2b  = h1p;                               // alias: h1p dead after gcn_gather

    hipMemsetAsync(ghist, 0, NCB_MAX * 4, stream);

    const int nbE = (E + EPB - 1) / EPB;
    const int nbScan = (N + SCAN_B - 1) / SCAN_B;

    // 1) CSR build: coarse hist -> scan -> privatized scatter -> fine counts
    //    -> N-scan -> block-local fill
    chist<<<nbE, 256, 0, stream>>>(coli, E, ghist, ncb);
    cscan<<<1, NCB_MAX, 0, stream>>>(ghist, cstart, gcursor, ncb, E);
    pass1_scatter<<<nbE, 256, 0, stream>>>(rowi, coli, E, gcursor, ebuf, ncb);
    pass2_count<<<ncb, 256, 0, stream>>>(ebuf, cstart, degi, N);
    scan_block<<<nbScan, SCAN_B, 0, stream>>>(degi, offsets, bsums, N);
    scan_bsums<<<1, 256, 0, stream>>>(bsums, nbScan);
    scan_finalize<<<(N + 256) / 256, 256, 0, stream>>>(degi, bsums, offsets, dinv, N, E);
    pass2_fill<<<ncb, 256, 0, stream>>>(ebuf, cstart, offsets, csr_src, N);

    // 2) operand prep
    wprep<<<12, 256, 0, stream>>>(W1, b1, wfrag, b1p);
    wprep2<<<4, 256, 0, stream>>>(Wg, bg, Wfc, wg2frag, bgp, wfcp);
    xprep<<<(N * 24 + 255) / 256, 256, 0, stream>>>(x, xb, N);

    // 3) h1p = perm-packed bf16((x @ W1) * dinv[row]) via LDS-free MFMA
    gemm1_mfma<<<(N + 63) / 64, 256, 0, stream>>>((const uint4*)xb, wfrag, dinv, h1p, N);

    // 4) GCN gather -> bf16 g (perm layout)
    gcn_gather<<<(N + 15) / 16, 256, 0, stream>>>(offsets, csr_src, (const uint4*)h1p,
                                                  dinv, b1p, gb, N);

    // 5) h2b = bf16(g @ Wg) via LDS-free MFMA, fused es/ed epilogue
    gemm2_mfma<<<(N + 63) / 64, 256, 0, stream>>>(gb, wg2frag, a_src, a_dst, h2b, es, ed, N);

    // 6) fused GAT: unnormalized-softmax gather + relu + final FC (bf16 h2 rows)
    gat_fused<<<(N + 31) / 32, 256, 0, stream>>>(offsets, csr_src, (const uint4*)h2b,
                                                 es, ed, bgp, wfcp, bfc, out, N);
}

// Round 11
// 352.783 us; speedup vs baseline: 1.8143x; 1.0971x over previous
//
#include <hip/hip_runtime.h>
#include <math.h>

#define NSL 0.2f   // leaky relu negative slope
#define IN_DIM 165
#define HID 128
#define OUT_H 64
#define NCB_MAX 512 // max coarse buckets (N <= 131072)
#define EPB 4096    // edges per pass1 block

typedef __attribute__((ext_vector_type(8))) short bf16x8;
typedef __attribute__((ext_vector_type(4))) float f32x4;

// ---------- bf16 pack (round-to-nearest-even) ----------
__device__ inline unsigned pack_bf16(float a, float b) {
    unsigned ua = __float_as_uint(a);
    ua += 0x7FFFu + ((ua >> 16) & 1u);
    unsigned ub = __float_as_uint(b);
    ub += 0x7FFFu + ((ub >> 16) & 1u);
    return (ua >> 16) | (ub & 0xFFFF0000u);
}

// column permutation of the packed layouts: stored bf16 index i -> original col.
__device__ __host__ inline int pcol(int i) {
    int j = i >> 1, odd = i & 1;
    return 32 * (j >> 4) + (j & 15) + 16 * odd;
}

// ---------- coarse histogram (LDS-privatized) ----------
__global__ __launch_bounds__(256) void chist(const int* __restrict__ coli, int E,
                                             int* __restrict__ ghist, int ncb) {
    __shared__ int h[NCB_MAX];
    for (int i = threadIdx.x; i < ncb; i += 256) h[i] = 0;
    __syncthreads();
    int e0 = blockIdx.x * EPB;
    int e1 = min(e0 + EPB, E);
    for (int e = e0 + threadIdx.x; e < e1; e += 256)
        atomicAdd(&h[coli[e] >> 8], 1);
    __syncthreads();
    for (int i = threadIdx.x; i < ncb; i += 256)
        if (h[i]) atomicAdd(&ghist[i], h[i]);
}

// ---------- 1-block scan of coarse histogram -> cstart, gcursor ----------
__global__ __launch_bounds__(NCB_MAX) void cscan(const int* __restrict__ ghist,
                                                 int* __restrict__ cstart,
                                                 int* __restrict__ gcursor,
                                                 int ncb, int E) {
    __shared__ int tmp[NCB_MAX];
    int tid = threadIdx.x;
    int v = (tid < ncb) ? ghist[tid] : 0;
    tmp[tid] = v;
    __syncthreads();
    for (int off = 1; off < NCB_MAX; off <<= 1) {
        int t = (tid >= off) ? tmp[tid - off] : 0;
        __syncthreads();
        tmp[tid] += t;
        __syncthreads();
    }
    if (tid < ncb) {
        int excl = tmp[tid] - v;
        cstart[tid] = excl;
        gcursor[tid] = excl;
    }
    if (tid == ncb - 1) cstart[ncb] = E;
}

// ---------- pass1: block-privatized scatter into coarse buckets ----------
// ebuf value = (row << 8) | (col & 255)   (requires N < 2^24)
__global__ __launch_bounds__(256) void pass1_scatter(const int* __restrict__ rowi,
                                                     const int* __restrict__ coli, int E,
                                                     int* __restrict__ gcursor,
                                                     unsigned* __restrict__ ebuf, int ncb) {
    __shared__ int hist[NCB_MAX];
    __shared__ int base[NCB_MAX];
    int e0 = blockIdx.x * EPB;
    int e1 = min(e0 + EPB, E);
    for (int i = threadIdx.x; i < ncb; i += 256) hist[i] = 0;
    __syncthreads();
    for (int e = e0 + threadIdx.x; e < e1; e += 256)
        atomicAdd(&hist[coli[e] >> 8], 1);
    __syncthreads();
    for (int i = threadIdx.x; i < ncb; i += 256) {
        int h = hist[i];
        base[i] = h ? atomicAdd(&gcursor[i], h) : 0;
        hist[i] = 0;
    }
    __syncthreads();
    for (int e = e0 + threadIdx.x; e < e1; e += 256) {
        int c = coli[e];
        int cb = c >> 8;
        int rank = atomicAdd(&hist[cb], 1);
        ebuf[base[cb] + rank] = ((unsigned)rowi[e] << 8) | (unsigned)(c & 255);
    }
}

// ---------- fused pass2: count -> local scan -> offsets/dinv -> rank+fill ----------
// One block per coarse bucket. offsets[node] = cstart[cb] + local exclusive
// prefix of fine counts (identical to the old global scan). Second ebuf pass
// is L1/L2-hot (bucket slice ~16 KB).
__global__ __launch_bounds__(256) void pass2_all(const unsigned* __restrict__ ebuf,
                                                 const int* __restrict__ cstart,
                                                 int* __restrict__ offsets,
                                                 float* __restrict__ dinv,
                                                 int* __restrict__ csr_src,
                                                 int n, int E) {
    __shared__ int cnt[256];
    __shared__ int scan[256];
    __shared__ int offs[256];
    const int tid = threadIdx.x;
    const int cb = blockIdx.x;
    cnt[tid] = 0;
    __syncthreads();
    int s = cstart[cb], e1 = cstart[cb + 1];
    for (int e = s + tid; e < e1; e += 256)
        atomicAdd(&cnt[ebuf[e] & 255u], 1);
    __syncthreads();
    int v = cnt[tid];
    scan[tid] = v;
    __syncthreads();
#pragma unroll
    for (int off = 1; off < 256; off <<= 1) {
        int t = (tid >= off) ? scan[tid - off] : 0;
        __syncthreads();
        scan[tid] += t;
        __syncthreads();
    }
    int off0 = s + scan[tid] - v;   // global exclusive offset for this node
    offs[tid] = off0;
    int node = (cb << 8) + tid;
    if (node < n) {
        offsets[node] = off0;
        dinv[node] = rsqrtf((float)v + 1.0f);   // +1 = self loop
    }
    if (cb == 0 && tid == 0) offsets[n] = E;
    cnt[tid] = 0;
    __syncthreads();
    for (int e = s + tid; e < e1; e += 256) {
        unsigned u = ebuf[e];
        int local = u & 255u;
        int rank = atomicAdd(&cnt[local], 1);
        csr_src[offs[local] + rank] = (int)(u >> 8);
    }
}

// ---------- weight prep (one dispatch): W1/Wg bf16 fragments + permuted b1/bg/Wfc ----------
__global__ __launch_bounds__(256) void wprep_all(const float* __restrict__ W1,
                                                 const float* __restrict__ b1,
                                                 const float* __restrict__ Wg,
                                                 const float* __restrict__ bg,
                                                 const float* __restrict__ Wfc,
                                                 uint4* __restrict__ wfrag,
                                                 float* __restrict__ b1p,
                                                 uint4* __restrict__ wg2frag,
                                                 float* __restrict__ bgp,
                                                 float2* __restrict__ wfcp) {
    int idx = blockIdx.x * 256 + threadIdx.x;
    if (idx < 3072) {
        // wfrag[(c*128 + n)*4 + q] = 8 bf16 of W1[c*32+q*8+j][n], k zero-padded
        int q = idx & 3, n = (idx >> 2) & 127, c = idx >> 9;
        int k0 = c * 32 + q * 8;
        float f[8];
#pragma unroll
        for (int j = 0; j < 8; j++) {
            int k = k0 + j;
            f[j] = (k < IN_DIM) ? W1[k * 128 + n] : 0.f;
        }
        uint4 u;
        u.x = pack_bf16(f[0], f[1]);
        u.y = pack_bf16(f[2], f[3]);
        u.z = pack_bf16(f[4], f[5]);
        u.w = pack_bf16(f[6], f[7]);
        wfrag[idx] = u;
    } else if (idx < 4096) {
        // wg2frag[(c*64 + n)*4 + q] = 8 bf16 of Wg[pcol(c*32+q*8+j)][n]
        int i2 = idx - 3072;
        int q = i2 & 3, n = (i2 >> 2) & 63, c = i2 >> 8;
        float f[8];
#pragma unroll
        for (int j = 0; j < 8; j++) {
            int ks = c * 32 + q * 8 + j;
            f[j] = Wg[pcol(ks) * 64 + n];
        }
        uint4 u;
        u.x = pack_bf16(f[0], f[1]);
        u.y = pack_bf16(f[2], f[3]);
        u.z = pack_bf16(f[4], f[5]);
        u.w = pack_bf16(f[6], f[7]);
        wg2frag[i2] = u;
    }
    if (idx < 128) b1p[idx] = b1[pcol(idx)];
    if (idx < 64) {
        int o = pcol(idx);
        bgp[idx] = bg[o];
        wfcp[idx] = make_float2(Wfc[o * 2], Wfc[o * 2 + 1]);
    }
}

// ---------- GEMM1 via bf16 MFMA, LDS-free, x read directly (fused cvt) ----------
// Wave w owns rows blockIdx*64 + w*16 .. +15, all 128 cols (8 acc tiles).
// A-frag built in-register from fp32 x (wave covers 16 contiguous rows -> the
// 10.5 KB slab is L1/L2-hot across the 6 K-chunks). B-frag from wfrag
// (identical across blocks -> L2-resident).
__global__ __launch_bounds__(256) void gemm1_mfma(const float* __restrict__ x,
                                                  const uint4* __restrict__ wfrag,
                                                  const float* __restrict__ dinv,
                                                  unsigned* __restrict__ h1p, int M) {
    const int t = threadIdx.x;
    const int wave = t >> 6;
    const int lane = t & 63;
    const int l16 = lane & 15;
    const int quad = lane >> 4;
    const int rowbase = blockIdx.x * 64 + wave * 16;

    int arow = rowbase + l16;
    if (arow >= M) arow = M - 1;
    const float* xr = x + (size_t)arow * IN_DIM;

    f32x4 acc[8];
#pragma unroll
    for (int nt = 0; nt < 8; nt++) acc[nt] = (f32x4){0.f, 0.f, 0.f, 0.f};

#pragma unroll
    for (int c = 0; c < 6; c++) {
        int k0 = c * 32 + quad * 8;
        float f[8];
#pragma unroll
        for (int j = 0; j < 8; j++)
            f[j] = (k0 + j < IN_DIM) ? xr[k0 + j] : 0.f;
        uint4 au;
        au.x = pack_bf16(f[0], f[1]);
        au.y = pack_bf16(f[2], f[3]);
        au.z = pack_bf16(f[4], f[5]);
        au.w = pack_bf16(f[6], f[7]);
        bf16x8 a = __builtin_bit_cast(bf16x8, au);
#pragma unroll
        for (int nt = 0; nt < 8; nt++) {
            uint4 bu = wfrag[(size_t)((c * 128 + nt * 16 + l16) * 4 + quad)];
            bf16x8 b = __builtin_bit_cast(bf16x8, bu);
            acc[nt] = __builtin_amdgcn_mfma_f32_16x16x32_bf16(a, b, acc[nt], 0, 0, 0);
        }
    }

#pragma unroll
    for (int r = 0; r < 4; r++) {
        int row = rowbase + quad * 4 + r;
        if (row < M) {
            float s = dinv[row];
#pragma unroll
            for (int p = 0; p < 4; p++) {
                h1p[(size_t)row * 64 + p * 16 + l16] =
                    pack_bf16(acc[2 * p][r] * s, acc[2 * p + 1][r] * s);
            }
        }
    }
}

__device__ inline void acc8(float* a, uint4 u) {
    a[0] += __uint_as_float(u.x << 16);
    a[1] += __uint_as_float(u.x & 0xFFFF0000u);
    a[2] += __uint_as_float(u.y << 16);
    a[3] += __uint_as_float(u.y & 0xFFFF0000u);
    a[4] += __uint_as_float(u.z << 16);
    a[5] += __uint_as_float(u.z & 0xFFFF0000u);
    a[6] += __uint_as_float(u.w << 16);
    a[7] += __uint_as_float(u.w & 0xFFFF0000u);
}

__device__ inline void fma8(float* a, uint4 u, float w) {
    a[0] = fmaf(__uint_as_float(u.x << 16), w, a[0]);
    a[1] = fmaf(__uint_as_float(u.x & 0xFFFF0000u), w, a[1]);
    a[2] = fmaf(__uint_as_float(u.y << 16), w, a[2]);
    a[3] = fmaf(__uint_as_float(u.y & 0xFFFF0000u), w, a[3]);
    a[4] = fmaf(__uint_as_float(u.z << 16), w, a[4]);
    a[5] = fmaf(__uint_as_float(u.z & 0xFFFF0000u), w, a[5]);
    a[6] = fmaf(__uint_as_float(u.w << 16), w, a[6]);
    a[7] = fmaf(__uint_as_float(u.w & 0xFFFF0000u), w, a[7]);
}

// ---------- GCN gather: quarter-wave per dst node, bf16 in, bf16 out ----------
__global__ __launch_bounds__(256) void gcn_gather(const int* __restrict__ offsets,
                                                  const int* __restrict__ csr_src,
                                                  const uint4* __restrict__ h1v,
                                                  const float* __restrict__ dinv,
                                                  const float* __restrict__ b1p,
                                                  uint4* __restrict__ gb, int n) {
    int node = (blockIdx.x * 256 + threadIdx.x) >> 4;
    int lane = threadIdx.x & 15;
    if (node >= n) return;
    int s0 = offsets[node], s1 = offsets[node + 1];

    float a0[8], a1[8], a2[8], a3[8];
#pragma unroll
    for (int i = 0; i < 8; i++) { a0[i] = 0.f; a1[i] = 0.f; a2[i] = 0.f; a3[i] = 0.f; }
    acc8(a0, h1v[(size_t)node * 16 + lane]);   // self loop (pre-scaled)

    int k = s0;
    for (; k + 4 <= s1; k += 4) {
        int r0 = csr_src[k], r1 = csr_src[k + 1], r2 = csr_src[k + 2], r3 = csr_src[k + 3];
        uint4 v0 = h1v[(size_t)r0 * 16 + lane];
        uint4 v1 = h1v[(size_t)r1 * 16 + lane];
        uint4 v2 = h1v[(size_t)r2 * 16 + lane];
        uint4 v3 = h1v[(size_t)r3 * 16 + lane];
        acc8(a0, v0);
        acc8(a1, v1);
        acc8(a2, v2);
        acc8(a3, v3);
    }
    for (; k < s1; k++) {
        int r = csr_src[k];
        acc8(a0, h1v[(size_t)r * 16 + lane]);
    }

    float dc = dinv[node];
    float4 bb0 = ((const float4*)b1p)[lane * 2];
    float4 bb1 = ((const float4*)b1p)[lane * 2 + 1];
    float o[8];
    o[0] = fmaxf(((a0[0] + a1[0]) + (a2[0] + a3[0])) * dc + bb0.x, 0.f);
    o[1] = fmaxf(((a0[1] + a1[1]) + (a2[1] + a3[1])) * dc + bb0.y, 0.f);
    o[2] = fmaxf(((a0[2] + a1[2]) + (a2[2] + a3[2])) * dc + bb0.z, 0.f);
    o[3] = fmaxf(((a0[3] + a1[3]) + (a2[3] + a3[3])) * dc + bb0.w, 0.f);
    o[4] = fmaxf(((a0[4] + a1[4]) + (a2[4] + a3[4])) * dc + bb1.x, 0.f);
    o[5] = fmaxf(((a0[5] + a1[5]) + (a2[5] + a3[5])) * dc + bb1.y, 0.f);
    o[6] = fmaxf(((a0[6] + a1[6]) + (a2[6] + a3[6])) * dc + bb1.z, 0.f);
    o[7] = fmaxf(((a0[7] + a1[7]) + (a2[7] + a3[7])) * dc + bb1.w, 0.f);
    uint4 pk;
    pk.x = pack_bf16(o[0], o[1]);
    pk.y = pack_bf16(o[2], o[3]);
    pk.z = pack_bf16(o[4], o[5]);
    pk.w = pack_bf16(o[6], o[7]);
    gb[(size_t)node * 16 + lane] = pk;
}

// ---------- GEMM2 via bf16 MFMA, LDS-free; fused es/ed; bf16 h2 out ----------
__global__ __launch_bounds__(256) void gemm2_mfma(const uint4* __restrict__ gb4,
                                                  const uint4* __restrict__ wg2frag,
                                                  const float* __restrict__ a_src,
                                                  const float* __restrict__ a_dst,
                                                  unsigned* __restrict__ h2b,
                                                  float* __restrict__ es,
                                                  float* __restrict__ ed, int M) {
    const int t = threadIdx.x;
    const int wave = t >> 6;
    const int lane = t & 63;
    const int l16 = lane & 15;
    const int quad = lane >> 4;
    const int rowbase = blockIdx.x * 64 + wave * 16;

    int arow = rowbase + l16;
    if (arow >= M) arow = M - 1;

    f32x4 acc[4];
#pragma unroll
    for (int nt = 0; nt < 4; nt++) acc[nt] = (f32x4){0.f, 0.f, 0.f, 0.f};

#pragma unroll
    for (int c = 0; c < 4; c++) {
        uint4 au = gb4[(size_t)arow * 16 + c * 4 + quad];
        bf16x8 a = __builtin_bit_cast(bf16x8, au);
#pragma unroll
        for (int nt = 0; nt < 4; nt++) {
            uint4 bu = wg2frag[(size_t)((c * 64 + nt * 16 + l16) * 4 + quad)];
            bf16x8 b = __builtin_bit_cast(bf16x8, bu);
            acc[nt] = __builtin_amdgcn_mfma_f32_16x16x32_bf16(a, b, acc[nt], 0, 0, 0);
        }
    }

    float as0 = a_src[l16], as1 = a_src[16 + l16], as2 = a_src[32 + l16], as3 = a_src[48 + l16];
    float ad0 = a_dst[l16], ad1 = a_dst[16 + l16], ad2 = a_dst[32 + l16], ad3 = a_dst[48 + l16];

#pragma unroll
    for (int r = 0; r < 4; r++) {
        int row = rowbase + quad * 4 + r;
        float ps = acc[0][r] * as0 + acc[1][r] * as1 + acc[2][r] * as2 + acc[3][r] * as3;
        float pd = acc[0][r] * ad0 + acc[1][r] * ad1 + acc[2][r] * ad2 + acc[3][r] * ad3;
#pragma unroll
        for (int m = 8; m; m >>= 1) {
            ps += __shfl_xor(ps, m, 16);
            pd += __shfl_xor(pd, m, 16);
        }
        if (row < M) {
            h2b[(size_t)row * 32 + l16]      = pack_bf16(acc[0][r], acc[1][r]);
            h2b[(size_t)row * 32 + 16 + l16] = pack_bf16(acc[2][r], acc[3][r]);
            if (l16 == 0) { es[row] = ps; ed[row] = pd; }
        }
    }
}

// ---------- fused GAT: 8 lanes per node, bf16 h2 rows, unnormalized softmax ----------
__global__ __launch_bounds__(256) void gat_fused(const int* __restrict__ offsets,
                                                 const int* __restrict__ csr_src,
                                                 const uint4* __restrict__ h2v,  // row = 8 uint4
                                                 const float* __restrict__ es,
                                                 const float* __restrict__ ed,
                                                 const float* __restrict__ bgp,
                                                 const float2* __restrict__ wfcp,
                                                 const float* __restrict__ bfc,
                                                 float* __restrict__ out, int n) {
    int node = (blockIdx.x * 256 + threadIdx.x) >> 3;
    int lane = threadIdx.x & 7;
    if (node >= n) return;
    int s0 = offsets[node], s1 = offsets[node + 1];
    float edc = ed[node];

    float eself = es[node] + edc;
    eself = eself > 0.f ? eself : NSL * eself;
    float x0s = __expf(eself);
    float sA = x0s, sB = 0.f, sC = 0.f, sD = 0.f;
    float aA[8], aB[8], aC[8], aD[8];
#pragma unroll
    for (int i = 0; i < 8; i++) { aA[i] = 0.f; aB[i] = 0.f; aC[i] = 0.f; aD[i] = 0.f; }
    fma8(aA, h2v[(size_t)node * 8 + lane], x0s);

    int k = s0;
    for (; k + 4 <= s1; k += 4) {
        int r0 = csr_src[k], r1 = csr_src[k + 1], r2 = csr_src[k + 2], r3 = csr_src[k + 3];
        float e0 = es[r0] + edc, e1 = es[r1] + edc, e2 = es[r2] + edc, e3 = es[r3] + edc;
        e0 = e0 > 0.f ? e0 : NSL * e0;
        e1 = e1 > 0.f ? e1 : NSL * e1;
        e2 = e2 > 0.f ? e2 : NSL * e2;
        e3 = e3 > 0.f ? e3 : NSL * e3;
        float x0 = __expf(e0), x1 = __expf(e1), x2 = __expf(e2), x3 = __expf(e3);
        uint4 v0 = h2v[(size_t)r0 * 8 + lane];
        uint4 v1 = h2v[(size_t)r1 * 8 + lane];
        uint4 v2 = h2v[(size_t)r2 * 8 + lane];
        uint4 v3 = h2v[(size_t)r3 * 8 + lane];
        sA += x0; sB += x1; sC += x2; sD += x3;
        fma8(aA, v0, x0);
        fma8(aB, v1, x1);
        fma8(aC, v2, x2);
        fma8(aD, v3, x3);
    }
    for (; k < s1; k++) {
        int r = csr_src[k];
        float e = es[r] + edc;
        e = e > 0.f ? e : NSL * e;
        float xv = __expf(e);
        sA += xv;
        fma8(aA, h2v[(size_t)r * 8 + lane], xv);
    }
    float s = (sA + sB) + (sC + sD);
    float rcp = 1.0f / s;
    float4 b0 = ((const float4*)bgp)[lane * 2];
    float4 b1 = ((const float4*)bgp)[lane * 2 + 1];
    float o[8];
    o[0] = fmaxf(((aA[0] + aB[0]) + (aC[0] + aD[0])) * rcp + b0.x, 0.f);
    o[1] = fmaxf(((aA[1] + aB[1]) + (aC[1] + aD[1])) * rcp + b0.y, 0.f);
    o[2] = fmaxf(((aA[2] + aB[2]) + (aC[2] + aD[2])) * rcp + b0.z, 0.f);
    o[3] = fmaxf(((aA[3] + aB[3]) + (aC[3] + aD[3])) * rcp + b0.w, 0.f);
    o[4] = fmaxf(((aA[4] + aB[4]) + (aC[4] + aD[4])) * rcp + b1.x, 0.f);
    o[5] = fmaxf(((aA[5] + aB[5]) + (aC[5] + aD[5])) * rcp + b1.y, 0.f);
    o[6] = fmaxf(((aA[6] + aB[6]) + (aC[6] + aD[6])) * rcp + b1.z, 0.f);
    o[7] = fmaxf(((aA[7] + aB[7]) + (aC[7] + aD[7])) * rcp + b1.w, 0.f);

    float p0 = 0.f, p1 = 0.f;
#pragma unroll
    for (int m2 = 0; m2 < 4; m2++) {
        float4 w = ((const float4*)wfcp)[lane * 4 + m2];
        p0 += o[2 * m2] * w.x + o[2 * m2 + 1] * w.z;
        p1 += o[2 * m2] * w.y + o[2 * m2 + 1] * w.w;
    }
#pragma unroll
    for (int m = 4; m; m >>= 1) {
        p0 += __shfl_xor(p0, m, 8);
        p1 += __shfl_xor(p1, m, 8);
    }
    if (lane == 0) {
        out[(size_t)node * 2 + 0] = p0 + bfc[0];
        out[(size_t)node * 2 + 1] = p1 + bfc[1];
    }
}

extern "C" void kernel_launch(void* const* d_in, const int* in_sizes, int n_in,
                              void* d_out, int out_size, void* d_ws, size_t ws_size,
                              hipStream_t stream) {
    const float* x     = (const float*)d_in[0];
    const int*   ei    = (const int*)d_in[1];
    const float* W1    = (const float*)d_in[2];
    const float* b1    = (const float*)d_in[3];
    const float* Wg    = (const float*)d_in[4];
    const float* a_src = (const float*)d_in[5];
    const float* a_dst = (const float*)d_in[6];
    const float* bg    = (const float*)d_in[7];
    const float* Wfc   = (const float*)d_in[8];
    const float* bfc   = (const float*)d_in[9];
    float* out = (float*)d_out;

    const int N = in_sizes[0] / IN_DIM;
    const int E = in_sizes[1] / 2;
    const int* rowi = ei;
    const int* coli = ei + E;
    const int ncb = (N + 255) >> 8;            // coarse buckets of 256 nodes

    auto alignup = [](char* p) { return (char*)(((uintptr_t)p + 15) & ~(uintptr_t)15); };

    // workspace layout, ~132N + 2E words ≈ 66 MB
    char* wsb = (char*)d_ws;
    int*   offsets = (int*)wsb;                         // N+8
    float* dinv    = (float*)(offsets + N + 8);         // N
    float* es      = dinv + N;                          // N
    float* ed      = es + N;                            // N
    int*   ghist   = (int*)(ed + N);                    // NCB_MAX
    int*   cstart  = ghist + NCB_MAX;                   // NCB_MAX+2
    int*   gcursor = cstart + NCB_MAX + 2;              // NCB_MAX
    float* b1p     = (float*)(gcursor + NCB_MAX);       // 128
    float* bgp     = b1p + 128;                         // 64
    float2* wfcp   = (float2*)(bgp + 64);               // 64 float2
    uint4* wfrag   = (uint4*)alignup((char*)(wfcp + 64));   // 3072 uint4 (48 KB)
    uint4* wg2frag = wfrag + 3072;                      // 1024 uint4 (16 KB)
    int*   csr_src = (int*)(wg2frag + 1024);            // E
    unsigned* ebuf = (unsigned*)(csr_src + E);          // E (packed row<<8|local)
    unsigned* h1p  = (unsigned*)alignup((char*)(ebuf + E)); // N*64 words (bf16 pairs, perm)
    uint4* gb      = (uint4*)alignup((char*)(h1p + (size_t)N * 64)); // N*16 uint4
    unsigned* h2b  = h1p;                               // alias: h1p dead after gcn_gather

    hipMemsetAsync(ghist, 0, NCB_MAX * 4, stream);

    const int nbE = (E + EPB - 1) / EPB;

    // 1) CSR build: coarse hist -> scan -> privatized scatter -> fused fine pass
    chist<<<nbE, 256, 0, stream>>>(coli, E, ghist, ncb);
    cscan<<<1, NCB_MAX, 0, stream>>>(ghist, cstart, gcursor, ncb, E);
    pass1_scatter<<<nbE, 256, 0, stream>>>(rowi, coli, E, gcursor, ebuf, ncb);
    pass2_all<<<ncb, 256, 0, stream>>>(ebuf, cstart, offsets, dinv, csr_src, N, E);

    // 2) weight prep (single dispatch)
    wprep_all<<<16, 256, 0, stream>>>(W1, b1, Wg, bg, Wfc, wfrag, b1p, wg2frag, bgp, wfcp);

    // 3) h1p = perm-packed bf16((x @ W1) * dinv[row]) via LDS-free MFMA (fused x cvt)
    gemm1_mfma<<<(N + 63) / 64, 256, 0, stream>>>(x, wfrag, dinv, h1p, N);

    // 4) GCN gather -> bf16 g (perm layout)
    gcn_gather<<<(N + 15) / 16, 256, 0, stream>>>(offsets, csr_src, (const uint4*)h1p,
                                                  dinv, b1p, gb, N);

    // 5) h2b = bf16(g @ Wg) via LDS-free MFMA, fused es/ed epilogue
    gemm2_mfma<<<(N + 63) / 64, 256, 0, stream>>>(gb, wg2frag, a_src, a_dst, h2b, es, ed, N);

    // 6) fused GAT: unnormalized-softmax gather + relu + final FC (bf16 h2 rows)
    gat_fused<<<(N + 31) / 32, 256, 0, stream>>>(offsets, csr_src, (const uint4*)h2b,
                                                 es, ed, bgp, wfcp, bfc, out, N);
}